// Round 7
// baseline (189.699 us; speedup 1.0000x reference)
//
#include <hip/hip_runtime.h>

#define N  512
#define E  256
#define H  150
#define HP 160
#define JB 64          // j per chunk
#define NCH (N / JB)   // 8

typedef __attribute__((ext_vector_type(8))) short short8;
typedef __attribute__((ext_vector_type(4))) float f32x4;
typedef __attribute__((ext_vector_type(4))) unsigned uint4v;
typedef __attribute__((ext_vector_type(2))) unsigned uint2v;

// Manual RNE f32->bf16 (verified numerics; __float22bfloat162_rn truncates here).
__device__ __forceinline__ unsigned short f2bf(float f) {
    unsigned u = __float_as_uint(f);
    u += 0x7fffu + ((u >> 16) & 1u);          // RNE
    return (unsigned short)(u >> 16);
}
__device__ __forceinline__ unsigned pkbf(float a, float b) {
    return (unsigned)f2bf(a) | ((unsigned)f2bf(b) << 16);
}

// ---------------- kernel 1: A[i,h]=g_i@W1a + b1 (f32), B[j,h]=g_j@W1b (bf16) ----------------
__global__ __launch_bounds__(192) void precompute_ab(
    const float* __restrict__ g, const float* __restrict__ W1,
    const float* __restrict__ b1, float* __restrict__ wsA,
    unsigned short* __restrict__ wsB)
{
    const int i0  = blockIdx.x * 4;
    const int tid = threadIdx.x;
    __shared__ float gi[4][E];
    for (int idx = tid; idx < 4 * E; idx += 192) gi[idx >> 8][idx & 255] = g[i0 * E + idx];
    __syncthreads();
    const int h = tid;
    if (h < HP) {
        float a[4] = {0, 0, 0, 0}, b[4] = {0, 0, 0, 0};
        if (h < H) {
            for (int e = 0; e < E; ++e) {
                const float wa = W1[e * H + h];
                const float wb = W1[(E + e) * H + h];
#pragma unroll
                for (int qq = 0; qq < 4; ++qq) {
                    a[qq] = fmaf(gi[qq][e], wa, a[qq]);
                    b[qq] = fmaf(gi[qq][e], wb, b[qq]);
                }
            }
            const float bb = b1[h];
#pragma unroll
            for (int qq = 0; qq < 4; ++qq) a[qq] += bb;
        }
#pragma unroll
        for (int qq = 0; qq < 4; ++qq) {
            wsA[(i0 + qq) * HP + h] = a[qq];
            wsB[(i0 + qq) * HP + h] = f2bf(b[qq]);
        }
    }
}

// ---------------- kernel 2: fused pairwise MFMA MLP ----------------
// R7 = R4's VERIFIED 3-barrier skeleton (A: P visible, B: h1 visible, C: end)
// + the provably-inert HALF of T14: global gj loads for chunk ch+1 are issued
// right after barrier A of chunk ch into registers (pure register prefetch of
// read-only data — touches no LDS, crosses no barrier semantics). The pack +
// ds_write stays EXACTLY where R4 had it (between barrier C and barrier A).
// NOTE (R5/R6 lesson): the 2-barrier structure with mid-chunk staging after
// barrier B raced twice (absmax 0.055 / 0.156) with no hazard found by
// inspection — do NOT retry it without a root-cause.
// 8 waves = 2 i x 4 h-quarters (wq mirrored for is=1 -> balanced SIMDs).
// 1 block/CU (register wall proven R1/R3). Dynamic LDS 125.25 KB.
#define OFF_P0   0        // P0 [64][528B] = 33792
#define OFF_P1   33792    // P1 [64][528B] -> 67584
#define OFF_H10  67584    // h1(i0) [64][336B] = 21504 -> 89088
#define OFF_H11  89088    // h1(i1) -> 110592
#define OFF_SB   110592   // [2][8][4][64] f32 = 16384 -> 126976
#define OFF_C2   126976   // b2 160 f32 = 640 -> 127616
#define OFF_W3L  127616   // W3 160 f32 = 640 -> 128256
#define LDS_SZ   128256
// transients (prologue only): W1t [150][272B]=40800, W2t [150][336B]=50400 — both < OFF_SB

__global__ __launch_bounds__(512, 2) void pairwise_mfma(
    const float* __restrict__ g,  const float* __restrict__ ms,
    const float* __restrict__ W1, const float* __restrict__ W2,
    const float* __restrict__ b2, const float* __restrict__ W3,
    const float* __restrict__ b3, const float* __restrict__ wsA,
    const unsigned short* __restrict__ wsB, float* __restrict__ out)
{
    extern __shared__ __attribute__((aligned(16))) char smem[];
    float* smf = (float*)smem;
    const int tid  = threadIdx.x;
    const int wave = tid >> 6;
    const int lane = tid & 63;
    const int c    = lane & 15;
    const int q    = lane >> 4;
    const int is   = wave >> 2;     // i-selector (0/1)
    const int wqr  = wave & 3;
    const int wq   = is ? (3 - wqr) : wqr;   // mirrored for SIMD load balance
    const int hbase  = (wq < 2) ? wq * 48 : 96 + (wq - 2) * 32;
    const int mcount = (wq < 2) ? 3 : 2;
    const short8 z8 = {0, 0, 0, 0, 0, 0, 0, 0};

    // ---- stage W1t (bf16 transposed, stride 272B) in 2 e-passes; 300 threads ----
    short8 w1f[3][8];
    for (int p = 0; p < 2; ++p) {
        if (p) __syncthreads();
        if (tid < 300) {
            const int h = (tid < 150) ? tid : tid - 150;
            const int half = (tid < 150) ? 0 : 1;
            const float* wsrc = W1 + (2 * E + p * 128) * H + h;
            char* dst = smem + h * 272 + half * 128;
#pragma unroll 4
            for (int t = 0; t < 32; ++t) {
                const int ep = half * 32 + t;
                *(unsigned*)(dst + t * 4) = pkbf(wsrc[(2 * ep) * H], wsrc[(2 * ep + 1) * H]);
            }
        }
        __syncthreads();
#pragma unroll
        for (int m = 0; m < 3; ++m) {
            const int hr = hbase + m * 16 + c;
#pragma unroll
            for (int ktp = 0; ktp < 4; ++ktp)
                w1f[m][p * 4 + ktp] = (m < mcount && hr < H)
                    ? *(const short8*)(smem + hr * 272 + (ktp * 32 + q * 8) * 2) : z8;
        }
    }
    __syncthreads();
    // ---- stage W2t (stride 336B); 300 threads; consts in parallel ----
    if (tid < 300) {
        const int h = (tid < 150) ? tid : tid - 150;
        const int half = (tid < 150) ? 0 : 1;
        char* dst = smem + h * 336;
#pragma unroll 4
        for (int t = 0; t < 42; ++t) {
            const int kp = half * 42 + t;
            const float lo = (2 * kp     < H) ? W2[(2 * kp) * H + h]     : 0.0f;
            const float hi = (2 * kp + 1 < H) ? W2[(2 * kp + 1) * H + h] : 0.0f;
            *(unsigned*)(dst + kp * 4) = pkbf(lo, hi);
        }
    }
    if (tid >= 320 && tid < 480) {
        const int hx = tid - 320;
        smf[OFF_C2 / 4 + hx]  = (hx < H) ? b2[hx] : 0.0f;
        smf[OFF_W3L / 4 + hx] = (hx < H) ? W3[hx] : 0.0f;
    }
    __syncthreads();
    short8 w2f[3][5];
#pragma unroll
    for (int m = 0; m < 3; ++m) {
        const int hr = hbase + m * 16 + c;
#pragma unroll
        for (int kt = 0; kt < 5; ++kt)
            w2f[m][kt] = (m < mcount && hr < H)
                ? *(const short8*)(smem + hr * 336 + (kt * 32 + q * 8) * 2) : z8;
    }
    __syncthreads();

    const int jb = tid >> 5;        // 0..15 (staging row group)
    const int e0 = (tid & 31) * 8;  // staging e-columns
    const float b3v = b3[0];
    const int i0 = blockIdx.x * 2;
    const int i  = i0 + is;         // this wave's compute i

    // staging scale vectors for BOTH i's (shared g-row loads feed both P buffers)
    const f32x4 ga0 = *(const f32x4*)(g + i0 * E + e0);
    const f32x4 gb0 = *(const f32x4*)(g + i0 * E + e0 + 4);
    const f32x4 ga1 = *(const f32x4*)(g + (i0 + 1) * E + e0);
    const f32x4 gb1 = *(const f32x4*)(g + (i0 + 1) * E + e0 + 4);

    f32x4 av[3];
#pragma unroll
    for (int m = 0; m < 3; ++m)
        av[m] = (m < mcount) ? *(const f32x4*)(wsA + i * HP + hbase + m * 16 + q * 4)
                             : (f32x4){0, 0, 0, 0};

    const int offP = is ? OFF_P1  : OFF_P0;
    const int offH = is ? OFF_H11 : OFF_H10;

    // ---- prologue: load chunk 0's gj rows into the prefetch registers ----
    f32x4 pu[4], pv[4];
#pragma unroll
    for (int it = 0; it < 4; ++it) {
        const float* gr = g + (jb + it * 16) * E + e0;
        pu[it] = *(const f32x4*)gr;
        pv[it] = *(const f32x4*)(gr + 4);
    }

    for (int ch = 0; ch < NCH; ++ch) {
        const int j0 = ch * JB;
        // ---- stage P(ch) from prefetched registers (R4 position: between C and A) ----
#pragma unroll
        for (int it = 0; it < 4; ++it) {
            const int jl = jb + it * 16;
            uint4v pk;
            pk[0] = pkbf(pu[it][0] * ga0[0], pu[it][1] * ga0[1]);
            pk[1] = pkbf(pu[it][2] * ga0[2], pu[it][3] * ga0[3]);
            pk[2] = pkbf(pv[it][0] * gb0[0], pv[it][1] * gb0[1]);
            pk[3] = pkbf(pv[it][2] * gb0[2], pv[it][3] * gb0[3]);
            *(uint4v*)(smem + OFF_P0 + jl * 528 + e0 * 2) = pk;
            pk[0] = pkbf(pu[it][0] * ga1[0], pu[it][1] * ga1[1]);
            pk[1] = pkbf(pu[it][2] * ga1[2], pu[it][3] * ga1[3]);
            pk[2] = pkbf(pv[it][0] * gb1[0], pv[it][1] * gb1[1]);
            pk[3] = pkbf(pv[it][2] * gb1[2], pv[it][3] * gb1[3]);
            *(uint4v*)(smem + OFF_P1 + jl * 528 + e0 * 2) = pk;
        }
        __syncthreads();   // barrier A: P(ch) visible

        // ---- T14 issue-early: register prefetch of gj for chunk ch+1
        //      (global, read-only, no LDS — drains under L1+L2 MFMAs) ----
        if (ch + 1 < NCH) {
#pragma unroll
            for (int it = 0; it < 4; ++it) {
                const float* gr = g + (j0 + JB + jb + it * 16) * E + e0;
                pu[it] = *(const f32x4*)gr;
                pv[it] = *(const f32x4*)(gr + 4);
            }
        }

        // ---- layer 1 + epi 1, two jt-passes (acc stays 24 regs) ----
#pragma unroll
        for (int jp = 0; jp < 2; ++jp) {
            f32x4 acc[2][3];
#pragma unroll
            for (int jt = 0; jt < 2; ++jt)
#pragma unroll
                for (int m = 0; m < 3; ++m) acc[jt][m] = (f32x4){0, 0, 0, 0};
#pragma unroll
            for (int kt = 0; kt < 8; ++kt) {
                short8 pf[2];
#pragma unroll
                for (int jt = 0; jt < 2; ++jt)
                    pf[jt] = *(const short8*)(smem + offP + ((jp * 2 + jt) * 16 + c) * 528 + (kt * 32 + q * 8) * 2);
#pragma unroll
                for (int m = 0; m < 3; ++m)
                    if (m < mcount)
#pragma unroll
                        for (int jt = 0; jt < 2; ++jt)
                            acc[jt][m] = __builtin_amdgcn_mfma_f32_16x16x32_bf16(w1f[m][kt], pf[jt], acc[jt][m], 0, 0, 0);
            }
#pragma unroll
            for (int m = 0; m < 3; ++m)
                if (m < mcount) {
                    const int h0 = hbase + m * 16 + q * 4;
#pragma unroll
                    for (int jt = 0; jt < 2; ++jt) {
                        const int j = (jp * 2 + jt) * 16 + c;
                        const uint2v bv = *(const uint2v*)(wsB + (j0 + j) * HP + h0);
                        const float v0 = fmaxf(acc[jt][m][0] + av[m][0] + __uint_as_float(bv[0] << 16), 0.0f);
                        const float v1 = fmaxf(acc[jt][m][1] + av[m][1] + __uint_as_float(bv[0] & 0xffff0000u), 0.0f);
                        const float v2 = fmaxf(acc[jt][m][2] + av[m][2] + __uint_as_float(bv[1] << 16), 0.0f);
                        const float v3 = fmaxf(acc[jt][m][3] + av[m][3] + __uint_as_float(bv[1] & 0xffff0000u), 0.0f);
                        uint2v hw;
                        hw[0] = pkbf(v0, v1);
                        hw[1] = pkbf(v2, v3);
                        *(uint2v*)(smem + offH + j * 336 + h0 * 2) = hw;
                    }
                }
        }
        __syncthreads();   // barrier B: h1 visible

        // ---- layer 2 + epi 2, two jt-passes ----
#pragma unroll
        for (int jp = 0; jp < 2; ++jp) {
            f32x4 acc[2][3];
#pragma unroll
            for (int jt = 0; jt < 2; ++jt)
#pragma unroll
                for (int m = 0; m < 3; ++m) acc[jt][m] = (f32x4){0, 0, 0, 0};
#pragma unroll
            for (int kt = 0; kt < 5; ++kt) {
                short8 hf[2];
#pragma unroll
                for (int jt = 0; jt < 2; ++jt)
                    hf[jt] = *(const short8*)(smem + offH + ((jp * 2 + jt) * 16 + c) * 336 + (kt * 32 + q * 8) * 2);
#pragma unroll
                for (int m = 0; m < 3; ++m)
                    if (m < mcount)
#pragma unroll
                        for (int jt = 0; jt < 2; ++jt)
                            acc[jt][m] = __builtin_amdgcn_mfma_f32_16x16x32_bf16(w2f[m][kt], hf[jt], acc[jt][m], 0, 0, 0);
            }
            float part[2] = {0.0f, 0.0f};
#pragma unroll
            for (int m = 0; m < 3; ++m)
                if (m < mcount) {
                    const int h0 = hbase + m * 16 + q * 4;
                    const f32x4 b2v = *(const f32x4*)(smf + OFF_C2 / 4 + h0);
                    const f32x4 w3v = *(const f32x4*)(smf + OFF_W3L / 4 + h0);
#pragma unroll
                    for (int jt = 0; jt < 2; ++jt)
#pragma unroll
                        for (int r = 0; r < 4; ++r)
                            part[jt] = fmaf(fmaxf(acc[jt][m][r] + b2v[r], 0.0f), w3v[r], part[jt]);
                }
#pragma unroll
            for (int jt = 0; jt < 2; ++jt) {
                float pv2 = part[jt];
                pv2 += __shfl_xor(pv2, 16);
                pv2 += __shfl_xor(pv2, 32);
                if (q == 0)
                    smf[OFF_SB / 4 + ((is * 8 + ch) * 4 + wq) * 64 + (jp * 2 + jt) * 16 + c] = pv2;
            }
        }
        __syncthreads();   // barrier C: SB visible; protects P/h1 re-stage next chunk
    }

    // ---- single coalesced flush: 2 stores/thread ----
    {
        const float msj = ms[tid];
        const int chf = tid >> 6, jl = tid & 63;
#pragma unroll
        for (int is2 = 0; is2 < 2; ++is2) {
            const int iw = i0 + is2;
            const int base = OFF_SB / 4 + ((is2 * 8 + chf) * 4) * 64 + jl;
            const float s = smf[base] + smf[base + 64] + smf[base + 128] + smf[base + 192] + b3v;
            out[iw * N + tid] = (ms[iw] + msj + s) * (1.0f / 3.0f);
        }
    }
}

extern "C" void kernel_launch(void* const* d_in, const int* in_sizes, int n_in,
                              void* d_out, int out_size, void* d_ws, size_t ws_size,
                              hipStream_t stream) {
    const float* g  = (const float*)d_in[0];
    const float* ms = (const float*)d_in[1];
    const float* W1 = (const float*)d_in[2];
    const float* b1 = (const float*)d_in[3];
    const float* W2 = (const float*)d_in[4];
    const float* b2 = (const float*)d_in[5];
    const float* W3 = (const float*)d_in[6];
    const float* b3 = (const float*)d_in[7];
    float* out = (float*)d_out;
    float* wsA = (float*)d_ws;                                         // 512*160 f32
    unsigned short* wsB = (unsigned short*)((char*)d_ws + N * HP * 4); // 512*160 bf16

    static bool attr_set = false;
    if (!attr_set) {
        hipFuncSetAttribute((const void*)pairwise_mfma,
                            hipFuncAttributeMaxDynamicSharedMemorySize, LDS_SZ);
        attr_set = true;
    }

    precompute_ab<<<N / 4, 192, 0, stream>>>(g, W1, b1, wsA, wsB);
    pairwise_mfma<<<N / 2, 512, LDS_SZ, stream>>>(g, ms, W1, W2, b2, W3, b3, wsA, wsB, out);
}

// Round 9
// 156.645 us; speedup vs baseline: 1.2110x; 1.2110x over previous
//
#include <hip/hip_runtime.h>

#define N  512
#define E  256
#define H  150
#define HP 160
#define JB 64          // j per chunk
#define NCH (N / JB)   // 8

typedef __attribute__((ext_vector_type(8))) short short8;
typedef __attribute__((ext_vector_type(4))) float f32x4;
typedef __attribute__((ext_vector_type(4))) unsigned uint4v;
typedef __attribute__((ext_vector_type(2))) unsigned uint2v;

// Manual RNE f32->bf16 (verified numerics; __float22bfloat162_rn truncates here).
__device__ __forceinline__ unsigned short f2bf(float f) {
    unsigned u = __float_as_uint(f);
    u += 0x7fffu + ((u >> 16) & 1u);          // RNE
    return (unsigned short)(u >> 16);
}
__device__ __forceinline__ unsigned pkbf(float a, float b) {
    return (unsigned)f2bf(a) | ((unsigned)f2bf(b) << 16);
}

// ---------------- kernel 1: A[i,h]=g_i@W1a + b1 (f32), B[j,h]=g_j@W1b (bf16) ----------------
// R9: the e-loop was ROLLED -> ~2 outstanding loads/thread -> ~256 x 220cy of
// serialized L2 latency per block at 1 wave/SIMD on half the CUs (~50-60us,
// hidden because it never made rocprof top-5). #pragma unroll 8 keeps the
// identical sequential FP accumulation order (no reassociation) -> wsA/wsB
// bit-identical -> absmax stays exactly 0.0078125; but gives the compiler 16
// independent loads per body to keep in flight.
__global__ __launch_bounds__(192) void precompute_ab(
    const float* __restrict__ g, const float* __restrict__ W1,
    const float* __restrict__ b1, float* __restrict__ wsA,
    unsigned short* __restrict__ wsB)
{
    const int i0  = blockIdx.x * 4;
    const int tid = threadIdx.x;
    __shared__ float gi[4][E];
    for (int idx = tid; idx < 4 * E; idx += 192) gi[idx >> 8][idx & 255] = g[i0 * E + idx];
    __syncthreads();
    const int h = tid;
    if (h < HP) {
        float a[4] = {0, 0, 0, 0}, b[4] = {0, 0, 0, 0};
        if (h < H) {
#pragma unroll 8
            for (int e = 0; e < E; ++e) {
                const float wa = W1[e * H + h];
                const float wb = W1[(E + e) * H + h];
#pragma unroll
                for (int qq = 0; qq < 4; ++qq) {
                    a[qq] = fmaf(gi[qq][e], wa, a[qq]);
                    b[qq] = fmaf(gi[qq][e], wb, b[qq]);
                }
            }
            const float bb = b1[h];
#pragma unroll
            for (int qq = 0; qq < 4; ++qq) a[qq] += bb;
        }
#pragma unroll
        for (int qq = 0; qq < 4; ++qq) {
            wsA[(i0 + qq) * HP + h] = a[qq];
            wsB[(i0 + qq) * HP + h] = f2bf(b[qq]);
        }
    }
}

// ---------------- kernel 2: fused pairwise MFMA MLP ----------------
// R4 VERBATIM — FROZEN. 8 waves = 2 i-groups x 4 h-quarters; each wave owns
// ONE i and computes all 64 j of the chunk (2 jt-passes of 2, acc 24 regs).
// Chunk g-rows loaded once, staged into BOTH P0/P1. 8 chunks, ~24 barriers.
// Occupancy 1 block/CU (register wall: w1f+w2f ~156 regs in unified VGPR/AGPR
// file caps at 2 waves/SIMD; R1/R3 proved 2-block residency unreachable).
// DO NOT touch the sync skeleton (stage->A->L1/epi1->B->L2/epi2->C): R5/R6/R8
// restructures raced (absmax 0.055/0.156/0.104) and R7's register prefetch
// spilled + shifted numerics — no root cause found; structure is frozen.
#define OFF_P0   0        // P0 [64][528B] = 33792
#define OFF_P1   33792    // P1 [64][528B] -> 67584
#define OFF_H10  67584    // h1(i0) [64][336B] = 21504 -> 89088
#define OFF_H11  89088    // h1(i1) -> 110592
#define OFF_SB   110592   // [2][8][4][64] f32 = 16384 -> 126976
#define OFF_C2   126976   // b2 160 f32 = 640 -> 127616
#define OFF_W3L  127616   // W3 160 f32 = 640 -> 128256
#define LDS_SZ   128256
// transients (prologue only): W1t [150][272B]=40800, W2t [150][336B]=50400 — both < OFF_SB

__global__ __launch_bounds__(512, 2) void pairwise_mfma(
    const float* __restrict__ g,  const float* __restrict__ ms,
    const float* __restrict__ W1, const float* __restrict__ W2,
    const float* __restrict__ b2, const float* __restrict__ W3,
    const float* __restrict__ b3, const float* __restrict__ wsA,
    const unsigned short* __restrict__ wsB, float* __restrict__ out)
{
    extern __shared__ __attribute__((aligned(16))) char smem[];
    float* smf = (float*)smem;
    const int tid  = threadIdx.x;
    const int wave = tid >> 6;
    const int lane = tid & 63;
    const int c    = lane & 15;
    const int q    = lane >> 4;
    const int is   = wave >> 2;     // i-selector (0/1)
    const int wqr  = wave & 3;
    const int wq   = is ? (3 - wqr) : wqr;   // mirrored for SIMD load balance
    const int hbase  = (wq < 2) ? wq * 48 : 96 + (wq - 2) * 32;
    const int mcount = (wq < 2) ? 3 : 2;
    const short8 z8 = {0, 0, 0, 0, 0, 0, 0, 0};

    // ---- stage W1t (bf16 transposed, stride 272B) in 2 e-passes; 300 threads ----
    short8 w1f[3][8];
    for (int p = 0; p < 2; ++p) {
        if (p) __syncthreads();
        if (tid < 300) {
            const int h = (tid < 150) ? tid : tid - 150;
            const int half = (tid < 150) ? 0 : 1;
            const float* wsrc = W1 + (2 * E + p * 128) * H + h;
            char* dst = smem + h * 272 + half * 128;
#pragma unroll 4
            for (int t = 0; t < 32; ++t) {
                const int ep = half * 32 + t;
                *(unsigned*)(dst + t * 4) = pkbf(wsrc[(2 * ep) * H], wsrc[(2 * ep + 1) * H]);
            }
        }
        __syncthreads();
#pragma unroll
        for (int m = 0; m < 3; ++m) {
            const int hr = hbase + m * 16 + c;
#pragma unroll
            for (int ktp = 0; ktp < 4; ++ktp)
                w1f[m][p * 4 + ktp] = (m < mcount && hr < H)
                    ? *(const short8*)(smem + hr * 272 + (ktp * 32 + q * 8) * 2) : z8;
        }
    }
    __syncthreads();
    // ---- stage W2t (stride 336B); 300 threads; consts in parallel ----
    if (tid < 300) {
        const int h = (tid < 150) ? tid : tid - 150;
        const int half = (tid < 150) ? 0 : 1;
        char* dst = smem + h * 336;
#pragma unroll 4
        for (int t = 0; t < 42; ++t) {
            const int kp = half * 42 + t;
            const float lo = (2 * kp     < H) ? W2[(2 * kp) * H + h]     : 0.0f;
            const float hi = (2 * kp + 1 < H) ? W2[(2 * kp + 1) * H + h] : 0.0f;
            *(unsigned*)(dst + kp * 4) = pkbf(lo, hi);
        }
    }
    if (tid >= 320 && tid < 480) {
        const int hx = tid - 320;
        smf[OFF_C2 / 4 + hx]  = (hx < H) ? b2[hx] : 0.0f;
        smf[OFF_W3L / 4 + hx] = (hx < H) ? W3[hx] : 0.0f;
    }
    __syncthreads();
    short8 w2f[3][5];
#pragma unroll
    for (int m = 0; m < 3; ++m) {
        const int hr = hbase + m * 16 + c;
#pragma unroll
        for (int kt = 0; kt < 5; ++kt)
            w2f[m][kt] = (m < mcount && hr < H)
                ? *(const short8*)(smem + hr * 336 + (kt * 32 + q * 8) * 2) : z8;
    }
    __syncthreads();

    const int jb = tid >> 5;        // 0..15 (staging row group)
    const int e0 = (tid & 31) * 8;  // staging e-columns
    const float b3v = b3[0];
    const int i0 = blockIdx.x * 2;
    const int i  = i0 + is;         // this wave's compute i

    // staging scale vectors for BOTH i's (shared g-row loads feed both P buffers)
    const f32x4 ga0 = *(const f32x4*)(g + i0 * E + e0);
    const f32x4 gb0 = *(const f32x4*)(g + i0 * E + e0 + 4);
    const f32x4 ga1 = *(const f32x4*)(g + (i0 + 1) * E + e0);
    const f32x4 gb1 = *(const f32x4*)(g + (i0 + 1) * E + e0 + 4);

    f32x4 av[3];
#pragma unroll
    for (int m = 0; m < 3; ++m)
        av[m] = (m < mcount) ? *(const f32x4*)(wsA + i * HP + hbase + m * 16 + q * 4)
                             : (f32x4){0, 0, 0, 0};

    const int offP = is ? OFF_P1  : OFF_P0;
    const int offH = is ? OFF_H11 : OFF_H10;

    for (int ch = 0; ch < NCH; ++ch) {
        const int j0 = ch * JB;
        // ---- stage P0[jl][e]=gj*gi0, P1[jl][e]=gj*gi1 (4 rows/thread, gj loaded once) ----
#pragma unroll
        for (int it = 0; it < 4; ++it) {
            const int jl = jb + it * 16;
            const float* gr = g + (j0 + jl) * E + e0;
            const f32x4 u = *(const f32x4*)gr;
            const f32x4 v = *(const f32x4*)(gr + 4);
            uint4v pk;
            pk[0] = pkbf(u[0] * ga0[0], u[1] * ga0[1]);
            pk[1] = pkbf(u[2] * ga0[2], u[3] * ga0[3]);
            pk[2] = pkbf(v[0] * gb0[0], v[1] * gb0[1]);
            pk[3] = pkbf(v[2] * gb0[2], v[3] * gb0[3]);
            *(uint4v*)(smem + OFF_P0 + jl * 528 + e0 * 2) = pk;
            pk[0] = pkbf(u[0] * ga1[0], u[1] * ga1[1]);
            pk[1] = pkbf(u[2] * ga1[2], u[3] * ga1[3]);
            pk[2] = pkbf(v[0] * gb1[0], v[1] * gb1[1]);
            pk[3] = pkbf(v[2] * gb1[2], v[3] * gb1[3]);
            *(uint4v*)(smem + OFF_P1 + jl * 528 + e0 * 2) = pk;
        }
        __syncthreads();   // barrier A: P0/P1 visible

        // ---- layer 1 + epi 1, two jt-passes (acc stays 24 regs) ----
#pragma unroll
        for (int jp = 0; jp < 2; ++jp) {
            f32x4 acc[2][3];
#pragma unroll
            for (int jt = 0; jt < 2; ++jt)
#pragma unroll
                for (int m = 0; m < 3; ++m) acc[jt][m] = (f32x4){0, 0, 0, 0};
#pragma unroll
            for (int kt = 0; kt < 8; ++kt) {
                short8 pf[2];
#pragma unroll
                for (int jt = 0; jt < 2; ++jt)
                    pf[jt] = *(const short8*)(smem + offP + ((jp * 2 + jt) * 16 + c) * 528 + (kt * 32 + q * 8) * 2);
#pragma unroll
                for (int m = 0; m < 3; ++m)
                    if (m < mcount)
#pragma unroll
                        for (int jt = 0; jt < 2; ++jt)
                            acc[jt][m] = __builtin_amdgcn_mfma_f32_16x16x32_bf16(w1f[m][kt], pf[jt], acc[jt][m], 0, 0, 0);
            }
#pragma unroll
            for (int m = 0; m < 3; ++m)
                if (m < mcount) {
                    const int h0 = hbase + m * 16 + q * 4;
#pragma unroll
                    for (int jt = 0; jt < 2; ++jt) {
                        const int j = (jp * 2 + jt) * 16 + c;
                        const uint2v bv = *(const uint2v*)(wsB + (j0 + j) * HP + h0);
                        const float v0 = fmaxf(acc[jt][m][0] + av[m][0] + __uint_as_float(bv[0] << 16), 0.0f);
                        const float v1 = fmaxf(acc[jt][m][1] + av[m][1] + __uint_as_float(bv[0] & 0xffff0000u), 0.0f);
                        const float v2 = fmaxf(acc[jt][m][2] + av[m][2] + __uint_as_float(bv[1] << 16), 0.0f);
                        const float v3 = fmaxf(acc[jt][m][3] + av[m][3] + __uint_as_float(bv[1] & 0xffff0000u), 0.0f);
                        uint2v hw;
                        hw[0] = pkbf(v0, v1);
                        hw[1] = pkbf(v2, v3);
                        *(uint2v*)(smem + offH + j * 336 + h0 * 2) = hw;
                    }
                }
        }
        __syncthreads();   // barrier B: h1(i0), h1(i1) visible

        // ---- layer 2 + epi 2, two jt-passes ----
#pragma unroll
        for (int jp = 0; jp < 2; ++jp) {
            f32x4 acc[2][3];
#pragma unroll
            for (int jt = 0; jt < 2; ++jt)
#pragma unroll
                for (int m = 0; m < 3; ++m) acc[jt][m] = (f32x4){0, 0, 0, 0};
#pragma unroll
            for (int kt = 0; kt < 5; ++kt) {
                short8 hf[2];
#pragma unroll
                for (int jt = 0; jt < 2; ++jt)
                    hf[jt] = *(const short8*)(smem + offH + ((jp * 2 + jt) * 16 + c) * 336 + (kt * 32 + q * 8) * 2);
#pragma unroll
                for (int m = 0; m < 3; ++m)
                    if (m < mcount)
#pragma unroll
                        for (int jt = 0; jt < 2; ++jt)
                            acc[jt][m] = __builtin_amdgcn_mfma_f32_16x16x32_bf16(w2f[m][kt], hf[jt], acc[jt][m], 0, 0, 0);
            }
            float part[2] = {0.0f, 0.0f};
#pragma unroll
            for (int m = 0; m < 3; ++m)
                if (m < mcount) {
                    const int h0 = hbase + m * 16 + q * 4;
                    const f32x4 b2v = *(const f32x4*)(smf + OFF_C2 / 4 + h0);
                    const f32x4 w3v = *(const f32x4*)(smf + OFF_W3L / 4 + h0);
#pragma unroll
                    for (int jt = 0; jt < 2; ++jt)
#pragma unroll
                        for (int r = 0; r < 4; ++r)
                            part[jt] = fmaf(fmaxf(acc[jt][m][r] + b2v[r], 0.0f), w3v[r], part[jt]);
                }
#pragma unroll
            for (int jt = 0; jt < 2; ++jt) {
                float pv = part[jt];
                pv += __shfl_xor(pv, 16);
                pv += __shfl_xor(pv, 32);
                if (q == 0)
                    smf[OFF_SB / 4 + ((is * 8 + ch) * 4 + wq) * 64 + (jp * 2 + jt) * 16 + c] = pv;
            }
        }
        __syncthreads();   // barrier C: SB slot written; also protects P/h1 re-stage next chunk
    }

    // ---- single coalesced flush: 2 stores/thread, no per-chunk global stores ----
    {
        const float msj = ms[tid];
        const int chf = tid >> 6, jl = tid & 63;
#pragma unroll
        for (int is2 = 0; is2 < 2; ++is2) {
            const int iw = i0 + is2;
            const int base = OFF_SB / 4 + ((is2 * 8 + chf) * 4) * 64 + jl;
            const float s = smf[base] + smf[base + 64] + smf[base + 128] + smf[base + 192] + b3v;
            out[iw * N + tid] = (ms[iw] + msj + s) * (1.0f / 3.0f);
        }
    }
}

extern "C" void kernel_launch(void* const* d_in, const int* in_sizes, int n_in,
                              void* d_out, int out_size, void* d_ws, size_t ws_size,
                              hipStream_t stream) {
    const float* g  = (const float*)d_in[0];
    const float* ms = (const float*)d_in[1];
    const float* W1 = (const float*)d_in[2];
    const float* b1 = (const float*)d_in[3];
    const float* W2 = (const float*)d_in[4];
    const float* b2 = (const float*)d_in[5];
    const float* W3 = (const float*)d_in[6];
    const float* b3 = (const float*)d_in[7];
    float* out = (float*)d_out;
    float* wsA = (float*)d_ws;                                         // 512*160 f32
    unsigned short* wsB = (unsigned short*)((char*)d_ws + N * HP * 4); // 512*160 bf16

    static bool attr_set = false;
    if (!attr_set) {
        hipFuncSetAttribute((const void*)pairwise_mfma,
                            hipFuncAttributeMaxDynamicSharedMemorySize, LDS_SZ);
        attr_set = true;
    }

    precompute_ab<<<N / 4, 192, 0, stream>>>(g, W1, b1, wsA, wsB);
    pairwise_mfma<<<N / 2, 512, LDS_SZ, stream>>>(g, ms, W1, W2, b2, W3, b3, wsA, wsB, out);
}

// Round 11
// 155.183 us; speedup vs baseline: 1.2224x; 1.0094x over previous
//
#include <hip/hip_runtime.h>

#define N  512
#define E  256
#define H  150
#define HP 160
#define JB 64          // j per chunk
#define NCH (N / JB)   // 8

typedef __attribute__((ext_vector_type(8))) short short8;
typedef __attribute__((ext_vector_type(4))) float f32x4;
typedef __attribute__((ext_vector_type(4))) unsigned uint4v;
typedef __attribute__((ext_vector_type(2))) unsigned uint2v;

// Manual RNE f32->bf16 (verified numerics; __float22bfloat162_rn truncates here).
__device__ __forceinline__ unsigned short f2bf(float f) {
    unsigned u = __float_as_uint(f);
    u += 0x7fffu + ((u >> 16) & 1u);          // RNE
    return (unsigned short)(u >> 16);
}
__device__ __forceinline__ unsigned pkbf(float a, float b) {
    return (unsigned)f2bf(a) | ((unsigned)f2bf(b) << 16);
}

// ---------------- kernel 1: A[i,h]=g_i@W1a + b1 (f32), B[j,h]=g_j@W1b (bf16) ----------------
// R9 VERBATIM (verified 156.6us, absmax exactly 0.0078125). The e-loop unroll
// keeps the identical sequential FP accumulation order -> wsA/wsB bit-exact.
// R10 LESSON: even semantically-inert changes elsewhere in this translation
// unit (setprio; co-compiled codegen perturbation per rule #19) have expressed
// a latent timing-sensitive hazard in kernel 2 (absmax 0.031-0.156 across
// R5/R6/R7/R8/R10). ENTIRE FILE FROZEN at the R9 state.
__global__ __launch_bounds__(192) void precompute_ab(
    const float* __restrict__ g, const float* __restrict__ W1,
    const float* __restrict__ b1, float* __restrict__ wsA,
    unsigned short* __restrict__ wsB)
{
    const int i0  = blockIdx.x * 4;
    const int tid = threadIdx.x;
    __shared__ float gi[4][E];
    for (int idx = tid; idx < 4 * E; idx += 192) gi[idx >> 8][idx & 255] = g[i0 * E + idx];
    __syncthreads();
    const int h = tid;
    if (h < HP) {
        float a[4] = {0, 0, 0, 0}, b[4] = {0, 0, 0, 0};
        if (h < H) {
#pragma unroll 8
            for (int e = 0; e < E; ++e) {
                const float wa = W1[e * H + h];
                const float wb = W1[(E + e) * H + h];
#pragma unroll
                for (int qq = 0; qq < 4; ++qq) {
                    a[qq] = fmaf(gi[qq][e], wa, a[qq]);
                    b[qq] = fmaf(gi[qq][e], wb, b[qq]);
                }
            }
            const float bb = b1[h];
#pragma unroll
            for (int qq = 0; qq < 4; ++qq) a[qq] += bb;
        }
#pragma unroll
        for (int qq = 0; qq < 4; ++qq) {
            wsA[(i0 + qq) * HP + h] = a[qq];
            wsB[(i0 + qq) * HP + h] = f2bf(b[qq]);
        }
    }
}

// ---------------- kernel 2: fused pairwise MFMA MLP ----------------
// R4/R9 VERBATIM — FROZEN. 8 waves = 2 i-groups x 4 h-quarters; each wave owns
// ONE i and computes all 64 j of the chunk (2 jt-passes of 2, acc 24 regs).
// Chunk g-rows loaded once, staged into BOTH P0/P1. 8 chunks, ~24 barriers.
// Occupancy 1 block/CU (register wall: w1f+w2f ~156 regs in unified VGPR/AGPR
// file caps at 2 waves/SIMD; R1/R3 proved 2-block residency unreachable).
// DO NOT MODIFY ANYTHING: R5/R6/R8 restructures raced (absmax .055/.156/.104),
// R7's register prefetch shifted numerics (.031), R10's setprio — a pure
// scheduler hint — shifted numerics (.096). A timing-sensitive hazard exists
// that this exact schedule masks; no root cause found in 5 audits.
#define OFF_P0   0        // P0 [64][528B] = 33792
#define OFF_P1   33792    // P1 [64][528B] -> 67584
#define OFF_H10  67584    // h1(i0) [64][336B] = 21504 -> 89088
#define OFF_H11  89088    // h1(i1) -> 110592
#define OFF_SB   110592   // [2][8][4][64] f32 = 16384 -> 126976
#define OFF_C2   126976   // b2 160 f32 = 640 -> 127616
#define OFF_W3L  127616   // W3 160 f32 = 640 -> 128256
#define LDS_SZ   128256
// transients (prologue only): W1t [150][272B]=40800, W2t [150][336B]=50400 — both < OFF_SB

__global__ __launch_bounds__(512, 2) void pairwise_mfma(
    const float* __restrict__ g,  const float* __restrict__ ms,
    const float* __restrict__ W1, const float* __restrict__ W2,
    const float* __restrict__ b2, const float* __restrict__ W3,
    const float* __restrict__ b3, const float* __restrict__ wsA,
    const unsigned short* __restrict__ wsB, float* __restrict__ out)
{
    extern __shared__ __attribute__((aligned(16))) char smem[];
    float* smf = (float*)smem;
    const int tid  = threadIdx.x;
    const int wave = tid >> 6;
    const int lane = tid & 63;
    const int c    = lane & 15;
    const int q    = lane >> 4;
    const int is   = wave >> 2;     // i-selector (0/1)
    const int wqr  = wave & 3;
    const int wq   = is ? (3 - wqr) : wqr;   // mirrored for SIMD load balance
    const int hbase  = (wq < 2) ? wq * 48 : 96 + (wq - 2) * 32;
    const int mcount = (wq < 2) ? 3 : 2;
    const short8 z8 = {0, 0, 0, 0, 0, 0, 0, 0};

    // ---- stage W1t (bf16 transposed, stride 272B) in 2 e-passes; 300 threads ----
    short8 w1f[3][8];
    for (int p = 0; p < 2; ++p) {
        if (p) __syncthreads();
        if (tid < 300) {
            const int h = (tid < 150) ? tid : tid - 150;
            const int half = (tid < 150) ? 0 : 1;
            const float* wsrc = W1 + (2 * E + p * 128) * H + h;
            char* dst = smem + h * 272 + half * 128;
#pragma unroll 4
            for (int t = 0; t < 32; ++t) {
                const int ep = half * 32 + t;
                *(unsigned*)(dst + t * 4) = pkbf(wsrc[(2 * ep) * H], wsrc[(2 * ep + 1) * H]);
            }
        }
        __syncthreads();
#pragma unroll
        for (int m = 0; m < 3; ++m) {
            const int hr = hbase + m * 16 + c;
#pragma unroll
            for (int ktp = 0; ktp < 4; ++ktp)
                w1f[m][p * 4 + ktp] = (m < mcount && hr < H)
                    ? *(const short8*)(smem + hr * 272 + (ktp * 32 + q * 8) * 2) : z8;
        }
    }
    __syncthreads();
    // ---- stage W2t (stride 336B); 300 threads; consts in parallel ----
    if (tid < 300) {
        const int h = (tid < 150) ? tid : tid - 150;
        const int half = (tid < 150) ? 0 : 1;
        char* dst = smem + h * 336;
#pragma unroll 4
        for (int t = 0; t < 42; ++t) {
            const int kp = half * 42 + t;
            const float lo = (2 * kp     < H) ? W2[(2 * kp) * H + h]     : 0.0f;
            const float hi = (2 * kp + 1 < H) ? W2[(2 * kp + 1) * H + h] : 0.0f;
            *(unsigned*)(dst + kp * 4) = pkbf(lo, hi);
        }
    }
    if (tid >= 320 && tid < 480) {
        const int hx = tid - 320;
        smf[OFF_C2 / 4 + hx]  = (hx < H) ? b2[hx] : 0.0f;
        smf[OFF_W3L / 4 + hx] = (hx < H) ? W3[hx] : 0.0f;
    }
    __syncthreads();
    short8 w2f[3][5];
#pragma unroll
    for (int m = 0; m < 3; ++m) {
        const int hr = hbase + m * 16 + c;
#pragma unroll
        for (int kt = 0; kt < 5; ++kt)
            w2f[m][kt] = (m < mcount && hr < H)
                ? *(const short8*)(smem + hr * 336 + (kt * 32 + q * 8) * 2) : z8;
    }
    __syncthreads();

    const int jb = tid >> 5;        // 0..15 (staging row group)
    const int e0 = (tid & 31) * 8;  // staging e-columns
    const float b3v = b3[0];
    const int i0 = blockIdx.x * 2;
    const int i  = i0 + is;         // this wave's compute i

    // staging scale vectors for BOTH i's (shared g-row loads feed both P buffers)
    const f32x4 ga0 = *(const f32x4*)(g + i0 * E + e0);
    const f32x4 gb0 = *(const f32x4*)(g + i0 * E + e0 + 4);
    const f32x4 ga1 = *(const f32x4*)(g + (i0 + 1) * E + e0);
    const f32x4 gb1 = *(const f32x4*)(g + (i0 + 1) * E + e0 + 4);

    f32x4 av[3];
#pragma unroll
    for (int m = 0; m < 3; ++m)
        av[m] = (m < mcount) ? *(const f32x4*)(wsA + i * HP + hbase + m * 16 + q * 4)
                             : (f32x4){0, 0, 0, 0};

    const int offP = is ? OFF_P1  : OFF_P0;
    const int offH = is ? OFF_H11 : OFF_H10;

    for (int ch = 0; ch < NCH; ++ch) {
        const int j0 = ch * JB;
        // ---- stage P0[jl][e]=gj*gi0, P1[jl][e]=gj*gi1 (4 rows/thread, gj loaded once) ----
#pragma unroll
        for (int it = 0; it < 4; ++it) {
            const int jl = jb + it * 16;
            const float* gr = g + (j0 + jl) * E + e0;
            const f32x4 u = *(const f32x4*)gr;
            const f32x4 v = *(const f32x4*)(gr + 4);
            uint4v pk;
            pk[0] = pkbf(u[0] * ga0[0], u[1] * ga0[1]);
            pk[1] = pkbf(u[2] * ga0[2], u[3] * ga0[3]);
            pk[2] = pkbf(v[0] * gb0[0], v[1] * gb0[1]);
            pk[3] = pkbf(v[2] * gb0[2], v[3] * gb0[3]);
            *(uint4v*)(smem + OFF_P0 + jl * 528 + e0 * 2) = pk;
            pk[0] = pkbf(u[0] * ga1[0], u[1] * ga1[1]);
            pk[1] = pkbf(u[2] * ga1[2], u[3] * ga1[3]);
            pk[2] = pkbf(v[0] * gb1[0], v[1] * gb1[1]);
            pk[3] = pkbf(v[2] * gb1[2], v[3] * gb1[3]);
            *(uint4v*)(smem + OFF_P1 + jl * 528 + e0 * 2) = pk;
        }
        __syncthreads();   // barrier A: P0/P1 visible

        // ---- layer 1 + epi 1, two jt-passes (acc stays 24 regs) ----
#pragma unroll
        for (int jp = 0; jp < 2; ++jp) {
            f32x4 acc[2][3];
#pragma unroll
            for (int jt = 0; jt < 2; ++jt)
#pragma unroll
                for (int m = 0; m < 3; ++m) acc[jt][m] = (f32x4){0, 0, 0, 0};
#pragma unroll
            for (int kt = 0; kt < 8; ++kt) {
                short8 pf[2];
#pragma unroll
                for (int jt = 0; jt < 2; ++jt)
                    pf[jt] = *(const short8*)(smem + offP + ((jp * 2 + jt) * 16 + c) * 528 + (kt * 32 + q * 8) * 2);
#pragma unroll
                for (int m = 0; m < 3; ++m)
                    if (m < mcount)
#pragma unroll
                        for (int jt = 0; jt < 2; ++jt)
                            acc[jt][m] = __builtin_amdgcn_mfma_f32_16x16x32_bf16(w1f[m][kt], pf[jt], acc[jt][m], 0, 0, 0);
            }
#pragma unroll
            for (int m = 0; m < 3; ++m)
                if (m < mcount) {
                    const int h0 = hbase + m * 16 + q * 4;
#pragma unroll
                    for (int jt = 0; jt < 2; ++jt) {
                        const int j = (jp * 2 + jt) * 16 + c;
                        const uint2v bv = *(const uint2v*)(wsB + (j0 + j) * HP + h0);
                        const float v0 = fmaxf(acc[jt][m][0] + av[m][0] + __uint_as_float(bv[0] << 16), 0.0f);
                        const float v1 = fmaxf(acc[jt][m][1] + av[m][1] + __uint_as_float(bv[0] & 0xffff0000u), 0.0f);
                        const float v2 = fmaxf(acc[jt][m][2] + av[m][2] + __uint_as_float(bv[1] << 16), 0.0f);
                        const float v3 = fmaxf(acc[jt][m][3] + av[m][3] + __uint_as_float(bv[1] & 0xffff0000u), 0.0f);
                        uint2v hw;
                        hw[0] = pkbf(v0, v1);
                        hw[1] = pkbf(v2, v3);
                        *(uint2v*)(smem + offH + j * 336 + h0 * 2) = hw;
                    }
                }
        }
        __syncthreads();   // barrier B: h1(i0), h1(i1) visible

        // ---- layer 2 + epi 2, two jt-passes ----
#pragma unroll
        for (int jp = 0; jp < 2; ++jp) {
            f32x4 acc[2][3];
#pragma unroll
            for (int jt = 0; jt < 2; ++jt)
#pragma unroll
                for (int m = 0; m < 3; ++m) acc[jt][m] = (f32x4){0, 0, 0, 0};
#pragma unroll
            for (int kt = 0; kt < 5; ++kt) {
                short8 hf[2];
#pragma unroll
                for (int jt = 0; jt < 2; ++jt)
                    hf[jt] = *(const short8*)(smem + offH + ((jp * 2 + jt) * 16 + c) * 336 + (kt * 32 + q * 8) * 2);
#pragma unroll
                for (int m = 0; m < 3; ++m)
                    if (m < mcount)
#pragma unroll
                        for (int jt = 0; jt < 2; ++jt)
                            acc[jt][m] = __builtin_amdgcn_mfma_f32_16x16x32_bf16(w2f[m][kt], hf[jt], acc[jt][m], 0, 0, 0);
            }
            float part[2] = {0.0f, 0.0f};
#pragma unroll
            for (int m = 0; m < 3; ++m)
                if (m < mcount) {
                    const int h0 = hbase + m * 16 + q * 4;
                    const f32x4 b2v = *(const f32x4*)(smf + OFF_C2 / 4 + h0);
                    const f32x4 w3v = *(const f32x4*)(smf + OFF_W3L / 4 + h0);
#pragma unroll
                    for (int jt = 0; jt < 2; ++jt)
#pragma unroll
                        for (int r = 0; r < 4; ++r)
                            part[jt] = fmaf(fmaxf(acc[jt][m][r] + b2v[r], 0.0f), w3v[r], part[jt]);
                }
#pragma unroll
            for (int jt = 0; jt < 2; ++jt) {
                float pv = part[jt];
                pv += __shfl_xor(pv, 16);
                pv += __shfl_xor(pv, 32);
                if (q == 0)
                    smf[OFF_SB / 4 + ((is * 8 + ch) * 4 + wq) * 64 + (jp * 2 + jt) * 16 + c] = pv;
            }
        }
        __syncthreads();   // barrier C: SB slot written; also protects P/h1 re-stage next chunk
    }

    // ---- single coalesced flush: 2 stores/thread, no per-chunk global stores ----
    {
        const float msj = ms[tid];
        const int chf = tid >> 6, jl = tid & 63;
#pragma unroll
        for (int is2 = 0; is2 < 2; ++is2) {
            const int iw = i0 + is2;
            const int base = OFF_SB / 4 + ((is2 * 8 + chf) * 4) * 64 + jl;
            const float s = smf[base] + smf[base + 64] + smf[base + 128] + smf[base + 192] + b3v;
            out[iw * N + tid] = (ms[iw] + msj + s) * (1.0f / 3.0f);
        }
    }
}

extern "C" void kernel_launch(void* const* d_in, const int* in_sizes, int n_in,
                              void* d_out, int out_size, void* d_ws, size_t ws_size,
                              hipStream_t stream) {
    const float* g  = (const float*)d_in[0];
    const float* ms = (const float*)d_in[1];
    const float* W1 = (const float*)d_in[2];
    const float* b1 = (const float*)d_in[3];
    const float* W2 = (const float*)d_in[4];
    const float* b2 = (const float*)d_in[5];
    const float* W3 = (const float*)d_in[6];
    const float* b3 = (const float*)d_in[7];
    float* out = (float*)d_out;
    float* wsA = (float*)d_ws;                                         // 512*160 f32
    unsigned short* wsB = (unsigned short*)((char*)d_ws + N * HP * 4); // 512*160 bf16

    static bool attr_set = false;
    if (!attr_set) {
        hipFuncSetAttribute((const void*)pairwise_mfma,
                            hipFuncAttributeMaxDynamicSharedMemorySize, LDS_SZ);
        attr_set = true;
    }

    precompute_ab<<<N / 4, 192, 0, stream>>>(g, W1, b1, wsA, wsB);
    pairwise_mfma<<<N / 2, 512, LDS_SZ, stream>>>(g, ms, W1, W2, b2, W3, b3, wsA, wsB, out);
}

// Round 12
// 153.541 us; speedup vs baseline: 1.2355x; 1.0107x over previous
//
#include <hip/hip_runtime.h>

#define N  512
#define E  256
#define H  150
#define HP 160
#define JB 64          // j per chunk
#define NCH (N / JB)   // 8

typedef __attribute__((ext_vector_type(8))) short short8;
typedef __attribute__((ext_vector_type(4))) float f32x4;
typedef __attribute__((ext_vector_type(4))) unsigned uint4v;
typedef __attribute__((ext_vector_type(2))) unsigned uint2v;

// Manual RNE f32->bf16 (verified numerics; __float22bfloat162_rn truncates here).
__device__ __forceinline__ unsigned short f2bf(float f) {
    unsigned u = __float_as_uint(f);
    u += 0x7fffu + ((u >> 16) & 1u);          // RNE
    return (unsigned short)(u >> 16);
}
__device__ __forceinline__ unsigned pkbf(float a, float b) {
    return (unsigned)f2bf(a) | ((unsigned)f2bf(b) << 16);
}

// ---------------- kernel 1: A[i,h]=g_i@W1a + b1 (f32), B[j,h]=g_j@W1b (bf16) ----------------
// R12 (ISOLATED change): 256 blocks x 2 i (was 128 x 4) -> 768 waves (3/CU)
// instead of 384 (1.5/CU), halving latency exposure of the strided W1 loads.
// Per-(i,h) FMA chain UNCHANGED in order/length -> wsA/wsB bit-identical.
// Kernel 2 source is BYTE-IDENTICAL to the verified R9/R11 state (separate
// __global__ functions compile independently -> its ISA/timing unchanged).
// R10 bundled this with setprio (the established hazard trigger); this round
// tests the kernel-1 lever alone, attributably.
__global__ __launch_bounds__(192) void precompute_ab(
    const float* __restrict__ g, const float* __restrict__ W1,
    const float* __restrict__ b1, float* __restrict__ wsA,
    unsigned short* __restrict__ wsB)
{
    const int i0  = blockIdx.x * 2;
    const int tid = threadIdx.x;
    __shared__ float gi[2][E];
    for (int idx = tid; idx < 2 * E; idx += 192) gi[idx >> 8][idx & 255] = g[i0 * E + idx];
    __syncthreads();
    const int h = tid;
    if (h < HP) {
        float a[2] = {0, 0}, b[2] = {0, 0};
        if (h < H) {
#pragma unroll 8
            for (int e = 0; e < E; ++e) {
                const float wa = W1[e * H + h];
                const float wb = W1[(E + e) * H + h];
#pragma unroll
                for (int qq = 0; qq < 2; ++qq) {
                    a[qq] = fmaf(gi[qq][e], wa, a[qq]);
                    b[qq] = fmaf(gi[qq][e], wb, b[qq]);
                }
            }
            const float bb = b1[h];
#pragma unroll
            for (int qq = 0; qq < 2; ++qq) a[qq] += bb;
        }
#pragma unroll
        for (int qq = 0; qq < 2; ++qq) {
            wsA[(i0 + qq) * HP + h] = a[qq];
            wsB[(i0 + qq) * HP + h] = f2bf(b[qq]);
        }
    }
}

// ---------------- kernel 2: fused pairwise MFMA MLP ----------------
// R4/R9 VERBATIM — FROZEN. 8 waves = 2 i-groups x 4 h-quarters; each wave owns
// ONE i and computes all 64 j of the chunk (2 jt-passes of 2, acc 24 regs).
// Chunk g-rows loaded once, staged into BOTH P0/P1. 8 chunks, ~24 barriers.
// Occupancy 1 block/CU (register wall: w1f+w2f ~156 regs in unified VGPR/AGPR
// file caps at 2 waves/SIMD; R1/R3 proved 2-block residency unreachable).
// DO NOT MODIFY ANYTHING: R5/R6/R8 restructures raced (absmax .055/.156/.104),
// R7's register prefetch shifted numerics (.031), R10's setprio — a pure
// scheduler hint — shifted numerics (.096). A timing-sensitive hazard exists
// that this exact schedule masks; no root cause found in 5 audits.
#define OFF_P0   0        // P0 [64][528B] = 33792
#define OFF_P1   33792    // P1 [64][528B] -> 67584
#define OFF_H10  67584    // h1(i0) [64][336B] = 21504 -> 89088
#define OFF_H11  89088    // h1(i1) -> 110592
#define OFF_SB   110592   // [2][8][4][64] f32 = 16384 -> 126976
#define OFF_C2   126976   // b2 160 f32 = 640 -> 127616
#define OFF_W3L  127616   // W3 160 f32 = 640 -> 128256
#define LDS_SZ   128256
// transients (prologue only): W1t [150][272B]=40800, W2t [150][336B]=50400 — both < OFF_SB

__global__ __launch_bounds__(512, 2) void pairwise_mfma(
    const float* __restrict__ g,  const float* __restrict__ ms,
    const float* __restrict__ W1, const float* __restrict__ W2,
    const float* __restrict__ b2, const float* __restrict__ W3,
    const float* __restrict__ b3, const float* __restrict__ wsA,
    const unsigned short* __restrict__ wsB, float* __restrict__ out)
{
    extern __shared__ __attribute__((aligned(16))) char smem[];
    float* smf = (float*)smem;
    const int tid  = threadIdx.x;
    const int wave = tid >> 6;
    const int lane = tid & 63;
    const int c    = lane & 15;
    const int q    = lane >> 4;
    const int is   = wave >> 2;     // i-selector (0/1)
    const int wqr  = wave & 3;
    const int wq   = is ? (3 - wqr) : wqr;   // mirrored for SIMD load balance
    const int hbase  = (wq < 2) ? wq * 48 : 96 + (wq - 2) * 32;
    const int mcount = (wq < 2) ? 3 : 2;
    const short8 z8 = {0, 0, 0, 0, 0, 0, 0, 0};

    // ---- stage W1t (bf16 transposed, stride 272B) in 2 e-passes; 300 threads ----
    short8 w1f[3][8];
    for (int p = 0; p < 2; ++p) {
        if (p) __syncthreads();
        if (tid < 300) {
            const int h = (tid < 150) ? tid : tid - 150;
            const int half = (tid < 150) ? 0 : 1;
            const float* wsrc = W1 + (2 * E + p * 128) * H + h;
            char* dst = smem + h * 272 + half * 128;
#pragma unroll 4
            for (int t = 0; t < 32; ++t) {
                const int ep = half * 32 + t;
                *(unsigned*)(dst + t * 4) = pkbf(wsrc[(2 * ep) * H], wsrc[(2 * ep + 1) * H]);
            }
        }
        __syncthreads();
#pragma unroll
        for (int m = 0; m < 3; ++m) {
            const int hr = hbase + m * 16 + c;
#pragma unroll
            for (int ktp = 0; ktp < 4; ++ktp)
                w1f[m][p * 4 + ktp] = (m < mcount && hr < H)
                    ? *(const short8*)(smem + hr * 272 + (ktp * 32 + q * 8) * 2) : z8;
        }
    }
    __syncthreads();
    // ---- stage W2t (stride 336B); 300 threads; consts in parallel ----
    if (tid < 300) {
        const int h = (tid < 150) ? tid : tid - 150;
        const int half = (tid < 150) ? 0 : 1;
        char* dst = smem + h * 336;
#pragma unroll 4
        for (int t = 0; t < 42; ++t) {
            const int kp = half * 42 + t;
            const float lo = (2 * kp     < H) ? W2[(2 * kp) * H + h]     : 0.0f;
            const float hi = (2 * kp + 1 < H) ? W2[(2 * kp + 1) * H + h] : 0.0f;
            *(unsigned*)(dst + kp * 4) = pkbf(lo, hi);
        }
    }
    if (tid >= 320 && tid < 480) {
        const int hx = tid - 320;
        smf[OFF_C2 / 4 + hx]  = (hx < H) ? b2[hx] : 0.0f;
        smf[OFF_W3L / 4 + hx] = (hx < H) ? W3[hx] : 0.0f;
    }
    __syncthreads();
    short8 w2f[3][5];
#pragma unroll
    for (int m = 0; m < 3; ++m) {
        const int hr = hbase + m * 16 + c;
#pragma unroll
        for (int kt = 0; kt < 5; ++kt)
            w2f[m][kt] = (m < mcount && hr < H)
                ? *(const short8*)(smem + hr * 336 + (kt * 32 + q * 8) * 2) : z8;
    }
    __syncthreads();

    const int jb = tid >> 5;        // 0..15 (staging row group)
    const int e0 = (tid & 31) * 8;  // staging e-columns
    const float b3v = b3[0];
    const int i0 = blockIdx.x * 2;
    const int i  = i0 + is;         // this wave's compute i

    // staging scale vectors for BOTH i's (shared g-row loads feed both P buffers)
    const f32x4 ga0 = *(const f32x4*)(g + i0 * E + e0);
    const f32x4 gb0 = *(const f32x4*)(g + i0 * E + e0 + 4);
    const f32x4 ga1 = *(const f32x4*)(g + (i0 + 1) * E + e0);
    const f32x4 gb1 = *(const f32x4*)(g + (i0 + 1) * E + e0 + 4);

    f32x4 av[3];
#pragma unroll
    for (int m = 0; m < 3; ++m)
        av[m] = (m < mcount) ? *(const f32x4*)(wsA + i * HP + hbase + m * 16 + q * 4)
                             : (f32x4){0, 0, 0, 0};

    const int offP = is ? OFF_P1  : OFF_P0;
    const int offH = is ? OFF_H11 : OFF_H10;

    for (int ch = 0; ch < NCH; ++ch) {
        const int j0 = ch * JB;
        // ---- stage P0[jl][e]=gj*gi0, P1[jl][e]=gj*gi1 (4 rows/thread, gj loaded once) ----
#pragma unroll
        for (int it = 0; it < 4; ++it) {
            const int jl = jb + it * 16;
            const float* gr = g + (j0 + jl) * E + e0;
            const f32x4 u = *(const f32x4*)gr;
            const f32x4 v = *(const f32x4*)(gr + 4);
            uint4v pk;
            pk[0] = pkbf(u[0] * ga0[0], u[1] * ga0[1]);
            pk[1] = pkbf(u[2] * ga0[2], u[3] * ga0[3]);
            pk[2] = pkbf(v[0] * gb0[0], v[1] * gb0[1]);
            pk[3] = pkbf(v[2] * gb0[2], v[3] * gb0[3]);
            *(uint4v*)(smem + OFF_P0 + jl * 528 + e0 * 2) = pk;
            pk[0] = pkbf(u[0] * ga1[0], u[1] * ga1[1]);
            pk[1] = pkbf(u[2] * ga1[2], u[3] * ga1[3]);
            pk[2] = pkbf(v[0] * gb1[0], v[1] * gb1[1]);
            pk[3] = pkbf(v[2] * gb1[2], v[3] * gb1[3]);
            *(uint4v*)(smem + OFF_P1 + jl * 528 + e0 * 2) = pk;
        }
        __syncthreads();   // barrier A: P0/P1 visible

        // ---- layer 1 + epi 1, two jt-passes (acc stays 24 regs) ----
#pragma unroll
        for (int jp = 0; jp < 2; ++jp) {
            f32x4 acc[2][3];
#pragma unroll
            for (int jt = 0; jt < 2; ++jt)
#pragma unroll
                for (int m = 0; m < 3; ++m) acc[jt][m] = (f32x4){0, 0, 0, 0};
#pragma unroll
            for (int kt = 0; kt < 8; ++kt) {
                short8 pf[2];
#pragma unroll
                for (int jt = 0; jt < 2; ++jt)
                    pf[jt] = *(const short8*)(smem + offP + ((jp * 2 + jt) * 16 + c) * 528 + (kt * 32 + q * 8) * 2);
#pragma unroll
                for (int m = 0; m < 3; ++m)
                    if (m < mcount)
#pragma unroll
                        for (int jt = 0; jt < 2; ++jt)
                            acc[jt][m] = __builtin_amdgcn_mfma_f32_16x16x32_bf16(w1f[m][kt], pf[jt], acc[jt][m], 0, 0, 0);
            }
#pragma unroll
            for (int m = 0; m < 3; ++m)
                if (m < mcount) {
                    const int h0 = hbase + m * 16 + q * 4;
#pragma unroll
                    for (int jt = 0; jt < 2; ++jt) {
                        const int j = (jp * 2 + jt) * 16 + c;
                        const uint2v bv = *(const uint2v*)(wsB + (j0 + j) * HP + h0);
                        const float v0 = fmaxf(acc[jt][m][0] + av[m][0] + __uint_as_float(bv[0] << 16), 0.0f);
                        const float v1 = fmaxf(acc[jt][m][1] + av[m][1] + __uint_as_float(bv[0] & 0xffff0000u), 0.0f);
                        const float v2 = fmaxf(acc[jt][m][2] + av[m][2] + __uint_as_float(bv[1] << 16), 0.0f);
                        const float v3 = fmaxf(acc[jt][m][3] + av[m][3] + __uint_as_float(bv[1] & 0xffff0000u), 0.0f);
                        uint2v hw;
                        hw[0] = pkbf(v0, v1);
                        hw[1] = pkbf(v2, v3);
                        *(uint2v*)(smem + offH + j * 336 + h0 * 2) = hw;
                    }
                }
        }
        __syncthreads();   // barrier B: h1(i0), h1(i1) visible

        // ---- layer 2 + epi 2, two jt-passes ----
#pragma unroll
        for (int jp = 0; jp < 2; ++jp) {
            f32x4 acc[2][3];
#pragma unroll
            for (int jt = 0; jt < 2; ++jt)
#pragma unroll
                for (int m = 0; m < 3; ++m) acc[jt][m] = (f32x4){0, 0, 0, 0};
#pragma unroll
            for (int kt = 0; kt < 5; ++kt) {
                short8 hf[2];
#pragma unroll
                for (int jt = 0; jt < 2; ++jt)
                    hf[jt] = *(const short8*)(smem + offH + ((jp * 2 + jt) * 16 + c) * 336 + (kt * 32 + q * 8) * 2);
#pragma unroll
                for (int m = 0; m < 3; ++m)
                    if (m < mcount)
#pragma unroll
                        for (int jt = 0; jt < 2; ++jt)
                            acc[jt][m] = __builtin_amdgcn_mfma_f32_16x16x32_bf16(w2f[m][kt], hf[jt], acc[jt][m], 0, 0, 0);
            }
            float part[2] = {0.0f, 0.0f};
#pragma unroll
            for (int m = 0; m < 3; ++m)
                if (m < mcount) {
                    const int h0 = hbase + m * 16 + q * 4;
                    const f32x4 b2v = *(const f32x4*)(smf + OFF_C2 / 4 + h0);
                    const f32x4 w3v = *(const f32x4*)(smf + OFF_W3L / 4 + h0);
#pragma unroll
                    for (int jt = 0; jt < 2; ++jt)
#pragma unroll
                        for (int r = 0; r < 4; ++r)
                            part[jt] = fmaf(fmaxf(acc[jt][m][r] + b2v[r], 0.0f), w3v[r], part[jt]);
                }
#pragma unroll
            for (int jt = 0; jt < 2; ++jt) {
                float pv = part[jt];
                pv += __shfl_xor(pv, 16);
                pv += __shfl_xor(pv, 32);
                if (q == 0)
                    smf[OFF_SB / 4 + ((is * 8 + ch) * 4 + wq) * 64 + (jp * 2 + jt) * 16 + c] = pv;
            }
        }
        __syncthreads();   // barrier C: SB slot written; also protects P/h1 re-stage next chunk
    }

    // ---- single coalesced flush: 2 stores/thread, no per-chunk global stores ----
    {
        const float msj = ms[tid];
        const int chf = tid >> 6, jl = tid & 63;
#pragma unroll
        for (int is2 = 0; is2 < 2; ++is2) {
            const int iw = i0 + is2;
            const int base = OFF_SB / 4 + ((is2 * 8 + chf) * 4) * 64 + jl;
            const float s = smf[base] + smf[base + 64] + smf[base + 128] + smf[base + 192] + b3v;
            out[iw * N + tid] = (ms[iw] + msj + s) * (1.0f / 3.0f);
        }
    }
}

extern "C" void kernel_launch(void* const* d_in, const int* in_sizes, int n_in,
                              void* d_out, int out_size, void* d_ws, size_t ws_size,
                              hipStream_t stream) {
    const float* g  = (const float*)d_in[0];
    const float* ms = (const float*)d_in[1];
    const float* W1 = (const float*)d_in[2];
    const float* b1 = (const float*)d_in[3];
    const float* W2 = (const float*)d_in[4];
    const float* b2 = (const float*)d_in[5];
    const float* W3 = (const float*)d_in[6];
    const float* b3 = (const float*)d_in[7];
    float* out = (float*)d_out;
    float* wsA = (float*)d_ws;                                         // 512*160 f32
    unsigned short* wsB = (unsigned short*)((char*)d_ws + N * HP * 4); // 512*160 bf16

    static bool attr_set = false;
    if (!attr_set) {
        hipFuncSetAttribute((const void*)pairwise_mfma,
                            hipFuncAttributeMaxDynamicSharedMemorySize, LDS_SZ);
        attr_set = true;
    }

    precompute_ab<<<N / 2, 192, 0, stream>>>(g, W1, b1, wsA, wsB);
    pairwise_mfma<<<N / 2, 512, LDS_SZ, stream>>>(g, ms, W1, W2, b2, W3, b3, wsA, wsB, out);
}

// Round 13
// 153.459 us; speedup vs baseline: 1.2362x; 1.0005x over previous
//
#include <hip/hip_runtime.h>

#define N  512
#define E  256
#define H  150
#define HP 160
#define JB 64          // j per chunk
#define NCH (N / JB)   // 8

typedef __attribute__((ext_vector_type(8))) short short8;
typedef __attribute__((ext_vector_type(4))) float f32x4;
typedef __attribute__((ext_vector_type(4))) unsigned uint4v;
typedef __attribute__((ext_vector_type(2))) unsigned uint2v;

// Manual RNE f32->bf16 (verified numerics; __float22bfloat162_rn truncates here).
__device__ __forceinline__ unsigned short f2bf(float f) {
    unsigned u = __float_as_uint(f);
    u += 0x7fffu + ((u >> 16) & 1u);          // RNE
    return (unsigned short)(u >> 16);
}
__device__ __forceinline__ unsigned pkbf(float a, float b) {
    return (unsigned)f2bf(a) | ((unsigned)f2bf(b) << 16);
}

// ---------------- kernel 1: A[i,h]=g_i@W1a + b1 (f32), B[j,h]=g_j@W1b (bf16) ----------------
// R13 (ISOLATED, same validated class as R12): 512 blocks x 1 i (was 256 x 2)
// -> 1536 waves (6/CU), halving residual latency exposure of the strided W1
// e-loop. Per-(i,h) FMA chain UNCHANGED in order/length -> wsA/wsB
// bit-identical. Kernel 2 source BYTE-IDENTICAL to verified R9/R11/R12 state
// (independent compilation validated by R12: all kernel-2 counters byte-stable).
__global__ __launch_bounds__(192) void precompute_ab(
    const float* __restrict__ g, const float* __restrict__ W1,
    const float* __restrict__ b1, float* __restrict__ wsA,
    unsigned short* __restrict__ wsB)
{
    const int i0  = blockIdx.x;
    const int tid = threadIdx.x;
    __shared__ float gi[E];
    for (int idx = tid; idx < E; idx += 192) gi[idx] = g[i0 * E + idx];
    __syncthreads();
    const int h = tid;
    if (h < HP) {
        float a = 0.0f, b = 0.0f;
        if (h < H) {
#pragma unroll 8
            for (int e = 0; e < E; ++e) {
                const float wa = W1[e * H + h];
                const float wb = W1[(E + e) * H + h];
                a = fmaf(gi[e], wa, a);
                b = fmaf(gi[e], wb, b);
            }
            a += b1[h];
        }
        wsA[i0 * HP + h] = a;
        wsB[i0 * HP + h] = f2bf(b);
    }
}

// ---------------- kernel 2: fused pairwise MFMA MLP ----------------
// R4/R9 VERBATIM — FROZEN. 8 waves = 2 i-groups x 4 h-quarters; each wave owns
// ONE i and computes all 64 j of the chunk (2 jt-passes of 2, acc 24 regs).
// Chunk g-rows loaded once, staged into BOTH P0/P1. 8 chunks, ~24 barriers.
// Occupancy 1 block/CU (register wall: w1f+w2f ~156 regs in unified VGPR/AGPR
// file caps at 2 waves/SIMD; R1/R3 proved 2-block residency unreachable).
// DO NOT MODIFY ANYTHING: R5/R6/R8 restructures raced (absmax .055/.156/.104),
// R7's register prefetch shifted numerics (.031), R10's setprio — a pure
// scheduler hint — shifted numerics (.096). A timing-sensitive hazard exists
// that this exact schedule masks; no root cause found in 5 audits.
#define OFF_P0   0        // P0 [64][528B] = 33792
#define OFF_P1   33792    // P1 [64][528B] -> 67584
#define OFF_H10  67584    // h1(i0) [64][336B] = 21504 -> 89088
#define OFF_H11  89088    // h1(i1) -> 110592
#define OFF_SB   110592   // [2][8][4][64] f32 = 16384 -> 126976
#define OFF_C2   126976   // b2 160 f32 = 640 -> 127616
#define OFF_W3L  127616   // W3 160 f32 = 640 -> 128256
#define LDS_SZ   128256
// transients (prologue only): W1t [150][272B]=40800, W2t [150][336B]=50400 — both < OFF_SB

__global__ __launch_bounds__(512, 2) void pairwise_mfma(
    const float* __restrict__ g,  const float* __restrict__ ms,
    const float* __restrict__ W1, const float* __restrict__ W2,
    const float* __restrict__ b2, const float* __restrict__ W3,
    const float* __restrict__ b3, const float* __restrict__ wsA,
    const unsigned short* __restrict__ wsB, float* __restrict__ out)
{
    extern __shared__ __attribute__((aligned(16))) char smem[];
    float* smf = (float*)smem;
    const int tid  = threadIdx.x;
    const int wave = tid >> 6;
    const int lane = tid & 63;
    const int c    = lane & 15;
    const int q    = lane >> 4;
    const int is   = wave >> 2;     // i-selector (0/1)
    const int wqr  = wave & 3;
    const int wq   = is ? (3 - wqr) : wqr;   // mirrored for SIMD load balance
    const int hbase  = (wq < 2) ? wq * 48 : 96 + (wq - 2) * 32;
    const int mcount = (wq < 2) ? 3 : 2;
    const short8 z8 = {0, 0, 0, 0, 0, 0, 0, 0};

    // ---- stage W1t (bf16 transposed, stride 272B) in 2 e-passes; 300 threads ----
    short8 w1f[3][8];
    for (int p = 0; p < 2; ++p) {
        if (p) __syncthreads();
        if (tid < 300) {
            const int h = (tid < 150) ? tid : tid - 150;
            const int half = (tid < 150) ? 0 : 1;
            const float* wsrc = W1 + (2 * E + p * 128) * H + h;
            char* dst = smem + h * 272 + half * 128;
#pragma unroll 4
            for (int t = 0; t < 32; ++t) {
                const int ep = half * 32 + t;
                *(unsigned*)(dst + t * 4) = pkbf(wsrc[(2 * ep) * H], wsrc[(2 * ep + 1) * H]);
            }
        }
        __syncthreads();
#pragma unroll
        for (int m = 0; m < 3; ++m) {
            const int hr = hbase + m * 16 + c;
#pragma unroll
            for (int ktp = 0; ktp < 4; ++ktp)
                w1f[m][p * 4 + ktp] = (m < mcount && hr < H)
                    ? *(const short8*)(smem + hr * 272 + (ktp * 32 + q * 8) * 2) : z8;
        }
    }
    __syncthreads();
    // ---- stage W2t (stride 336B); 300 threads; consts in parallel ----
    if (tid < 300) {
        const int h = (tid < 150) ? tid : tid - 150;
        const int half = (tid < 150) ? 0 : 1;
        char* dst = smem + h * 336;
#pragma unroll 4
        for (int t = 0; t < 42; ++t) {
            const int kp = half * 42 + t;
            const float lo = (2 * kp     < H) ? W2[(2 * kp) * H + h]     : 0.0f;
            const float hi = (2 * kp + 1 < H) ? W2[(2 * kp + 1) * H + h] : 0.0f;
            *(unsigned*)(dst + kp * 4) = pkbf(lo, hi);
        }
    }
    if (tid >= 320 && tid < 480) {
        const int hx = tid - 320;
        smf[OFF_C2 / 4 + hx]  = (hx < H) ? b2[hx] : 0.0f;
        smf[OFF_W3L / 4 + hx] = (hx < H) ? W3[hx] : 0.0f;
    }
    __syncthreads();
    short8 w2f[3][5];
#pragma unroll
    for (int m = 0; m < 3; ++m) {
        const int hr = hbase + m * 16 + c;
#pragma unroll
        for (int kt = 0; kt < 5; ++kt)
            w2f[m][kt] = (m < mcount && hr < H)
                ? *(const short8*)(smem + hr * 336 + (kt * 32 + q * 8) * 2) : z8;
    }
    __syncthreads();

    const int jb = tid >> 5;        // 0..15 (staging row group)
    const int e0 = (tid & 31) * 8;  // staging e-columns
    const float b3v = b3[0];
    const int i0 = blockIdx.x * 2;
    const int i  = i0 + is;         // this wave's compute i

    // staging scale vectors for BOTH i's (shared g-row loads feed both P buffers)
    const f32x4 ga0 = *(const f32x4*)(g + i0 * E + e0);
    const f32x4 gb0 = *(const f32x4*)(g + i0 * E + e0 + 4);
    const f32x4 ga1 = *(const f32x4*)(g + (i0 + 1) * E + e0);
    const f32x4 gb1 = *(const f32x4*)(g + (i0 + 1) * E + e0 + 4);

    f32x4 av[3];
#pragma unroll
    for (int m = 0; m < 3; ++m)
        av[m] = (m < mcount) ? *(const f32x4*)(wsA + i * HP + hbase + m * 16 + q * 4)
                             : (f32x4){0, 0, 0, 0};

    const int offP = is ? OFF_P1  : OFF_P0;
    const int offH = is ? OFF_H11 : OFF_H10;

    for (int ch = 0; ch < NCH; ++ch) {
        const int j0 = ch * JB;
        // ---- stage P0[jl][e]=gj*gi0, P1[jl][e]=gj*gi1 (4 rows/thread, gj loaded once) ----
#pragma unroll
        for (int it = 0; it < 4; ++it) {
            const int jl = jb + it * 16;
            const float* gr = g + (j0 + jl) * E + e0;
            const f32x4 u = *(const f32x4*)gr;
            const f32x4 v = *(const f32x4*)(gr + 4);
            uint4v pk;
            pk[0] = pkbf(u[0] * ga0[0], u[1] * ga0[1]);
            pk[1] = pkbf(u[2] * ga0[2], u[3] * ga0[3]);
            pk[2] = pkbf(v[0] * gb0[0], v[1] * gb0[1]);
            pk[3] = pkbf(v[2] * gb0[2], v[3] * gb0[3]);
            *(uint4v*)(smem + OFF_P0 + jl * 528 + e0 * 2) = pk;
            pk[0] = pkbf(u[0] * ga1[0], u[1] * ga1[1]);
            pk[1] = pkbf(u[2] * ga1[2], u[3] * ga1[3]);
            pk[2] = pkbf(v[0] * gb1[0], v[1] * gb1[1]);
            pk[3] = pkbf(v[2] * gb1[2], v[3] * gb1[3]);
            *(uint4v*)(smem + OFF_P1 + jl * 528 + e0 * 2) = pk;
        }
        __syncthreads();   // barrier A: P0/P1 visible

        // ---- layer 1 + epi 1, two jt-passes (acc stays 24 regs) ----
#pragma unroll
        for (int jp = 0; jp < 2; ++jp) {
            f32x4 acc[2][3];
#pragma unroll
            for (int jt = 0; jt < 2; ++jt)
#pragma unroll
                for (int m = 0; m < 3; ++m) acc[jt][m] = (f32x4){0, 0, 0, 0};
#pragma unroll
            for (int kt = 0; kt < 8; ++kt) {
                short8 pf[2];
#pragma unroll
                for (int jt = 0; jt < 2; ++jt)
                    pf[jt] = *(const short8*)(smem + offP + ((jp * 2 + jt) * 16 + c) * 528 + (kt * 32 + q * 8) * 2);
#pragma unroll
                for (int m = 0; m < 3; ++m)
                    if (m < mcount)
#pragma unroll
                        for (int jt = 0; jt < 2; ++jt)
                            acc[jt][m] = __builtin_amdgcn_mfma_f32_16x16x32_bf16(w1f[m][kt], pf[jt], acc[jt][m], 0, 0, 0);
            }
#pragma unroll
            for (int m = 0; m < 3; ++m)
                if (m < mcount) {
                    const int h0 = hbase + m * 16 + q * 4;
#pragma unroll
                    for (int jt = 0; jt < 2; ++jt) {
                        const int j = (jp * 2 + jt) * 16 + c;
                        const uint2v bv = *(const uint2v*)(wsB + (j0 + j) * HP + h0);
                        const float v0 = fmaxf(acc[jt][m][0] + av[m][0] + __uint_as_float(bv[0] << 16), 0.0f);
                        const float v1 = fmaxf(acc[jt][m][1] + av[m][1] + __uint_as_float(bv[0] & 0xffff0000u), 0.0f);
                        const float v2 = fmaxf(acc[jt][m][2] + av[m][2] + __uint_as_float(bv[1] << 16), 0.0f);
                        const float v3 = fmaxf(acc[jt][m][3] + av[m][3] + __uint_as_float(bv[1] & 0xffff0000u), 0.0f);
                        uint2v hw;
                        hw[0] = pkbf(v0, v1);
                        hw[1] = pkbf(v2, v3);
                        *(uint2v*)(smem + offH + j * 336 + h0 * 2) = hw;
                    }
                }
        }
        __syncthreads();   // barrier B: h1(i0), h1(i1) visible

        // ---- layer 2 + epi 2, two jt-passes ----
#pragma unroll
        for (int jp = 0; jp < 2; ++jp) {
            f32x4 acc[2][3];
#pragma unroll
            for (int jt = 0; jt < 2; ++jt)
#pragma unroll
                for (int m = 0; m < 3; ++m) acc[jt][m] = (f32x4){0, 0, 0, 0};
#pragma unroll
            for (int kt = 0; kt < 5; ++kt) {
                short8 hf[2];
#pragma unroll
                for (int jt = 0; jt < 2; ++jt)
                    hf[jt] = *(const short8*)(smem + offH + ((jp * 2 + jt) * 16 + c) * 336 + (kt * 32 + q * 8) * 2);
#pragma unroll
                for (int m = 0; m < 3; ++m)
                    if (m < mcount)
#pragma unroll
                        for (int jt = 0; jt < 2; ++jt)
                            acc[jt][m] = __builtin_amdgcn_mfma_f32_16x16x32_bf16(w2f[m][kt], hf[jt], acc[jt][m], 0, 0, 0);
            }
            float part[2] = {0.0f, 0.0f};
#pragma unroll
            for (int m = 0; m < 3; ++m)
                if (m < mcount) {
                    const int h0 = hbase + m * 16 + q * 4;
                    const f32x4 b2v = *(const f32x4*)(smf + OFF_C2 / 4 + h0);
                    const f32x4 w3v = *(const f32x4*)(smf + OFF_W3L / 4 + h0);
#pragma unroll
                    for (int jt = 0; jt < 2; ++jt)
#pragma unroll
                        for (int r = 0; r < 4; ++r)
                            part[jt] = fmaf(fmaxf(acc[jt][m][r] + b2v[r], 0.0f), w3v[r], part[jt]);
                }
#pragma unroll
            for (int jt = 0; jt < 2; ++jt) {
                float pv = part[jt];
                pv += __shfl_xor(pv, 16);
                pv += __shfl_xor(pv, 32);
                if (q == 0)
                    smf[OFF_SB / 4 + ((is * 8 + ch) * 4 + wq) * 64 + (jp * 2 + jt) * 16 + c] = pv;
            }
        }
        __syncthreads();   // barrier C: SB slot written; also protects P/h1 re-stage next chunk
    }

    // ---- single coalesced flush: 2 stores/thread, no per-chunk global stores ----
    {
        const float msj = ms[tid];
        const int chf = tid >> 6, jl = tid & 63;
#pragma unroll
        for (int is2 = 0; is2 < 2; ++is2) {
            const int iw = i0 + is2;
            const int base = OFF_SB / 4 + ((is2 * 8 + chf) * 4) * 64 + jl;
            const float s = smf[base] + smf[base + 64] + smf[base + 128] + smf[base + 192] + b3v;
            out[iw * N + tid] = (ms[iw] + msj + s) * (1.0f / 3.0f);
        }
    }
}

extern "C" void kernel_launch(void* const* d_in, const int* in_sizes, int n_in,
                              void* d_out, int out_size, void* d_ws, size_t ws_size,
                              hipStream_t stream) {
    const float* g  = (const float*)d_in[0];
    const float* ms = (const float*)d_in[1];
    const float* W1 = (const float*)d_in[2];
    const float* b1 = (const float*)d_in[3];
    const float* W2 = (const float*)d_in[4];
    const float* b2 = (const float*)d_in[5];
    const float* W3 = (const float*)d_in[6];
    const float* b3 = (const float*)d_in[7];
    float* out = (float*)d_out;
    float* wsA = (float*)d_ws;                                         // 512*160 f32
    unsigned short* wsB = (unsigned short*)((char*)d_ws + N * HP * 4); // 512*160 bf16

    static bool attr_set = false;
    if (!attr_set) {
        hipFuncSetAttribute((const void*)pairwise_mfma,
                            hipFuncAttributeMaxDynamicSharedMemorySize, LDS_SZ);
        attr_set = true;
    }

    precompute_ab<<<N, 192, 0, stream>>>(g, W1, b1, wsA, wsB);
    pairwise_mfma<<<N / 2, 512, LDS_SZ, stream>>>(g, ms, W1, W2, b2, W3, b3, wsA, wsB, out);
}

// Round 14
// 152.653 us; speedup vs baseline: 1.2427x; 1.0053x over previous
//
#include <hip/hip_runtime.h>

#define N  512
#define E  256
#define H  150
#define HP 160
#define JB 64          // j per chunk
#define NCH (N / JB)   // 8

typedef __attribute__((ext_vector_type(8))) short short8;
typedef __attribute__((ext_vector_type(4))) float f32x4;
typedef __attribute__((ext_vector_type(4))) unsigned uint4v;
typedef __attribute__((ext_vector_type(2))) unsigned uint2v;

// Manual RNE f32->bf16 (verified numerics; __float22bfloat162_rn truncates here).
__device__ __forceinline__ unsigned short f2bf(float f) {
    unsigned u = __float_as_uint(f);
    u += 0x7fffu + ((u >> 16) & 1u);          // RNE
    return (unsigned short)(u >> 16);
}
__device__ __forceinline__ unsigned pkbf(float a, float b) {
    return (unsigned)f2bf(a) | ((unsigned)f2bf(b) << 16);
}

// ---------------- kernel 1: A[i,h]=g_i@W1a + b1 (f32), B[j,h]=g_j@W1b (bf16) ----------------
// TERMINAL STATE (R13, verified 153.46us): 512 blocks x 1 i -> 1536 waves
// (6/CU). Per-(i,h) FMA chain order/length fixed across R9/R12/R13 -> wsA/wsB
// bit-identical at every step; kernel-1 latency taken ~60us -> ~5us over the
// session (R9 unroll, R12/R13 TLP). Axis exhausted (R13 delta within noise).
__global__ __launch_bounds__(192) void precompute_ab(
    const float* __restrict__ g, const float* __restrict__ W1,
    const float* __restrict__ b1, float* __restrict__ wsA,
    unsigned short* __restrict__ wsB)
{
    const int i0  = blockIdx.x;
    const int tid = threadIdx.x;
    __shared__ float gi[E];
    for (int idx = tid; idx < E; idx += 192) gi[idx] = g[i0 * E + idx];
    __syncthreads();
    const int h = tid;
    if (h < HP) {
        float a = 0.0f, b = 0.0f;
        if (h < H) {
#pragma unroll 8
            for (int e = 0; e < E; ++e) {
                const float wa = W1[e * H + h];
                const float wb = W1[(E + e) * H + h];
                a = fmaf(gi[e], wa, a);
                b = fmaf(gi[e], wb, b);
            }
            a += b1[h];
        }
        wsA[i0 * HP + h] = a;
        wsB[i0 * HP + h] = f2bf(b);
    }
}

// ---------------- kernel 2: fused pairwise MFMA MLP ----------------
// R4/R9 VERBATIM — FROZEN (passed 5x at absmax exactly 0.0078125).
// 8 waves = 2 i-groups x 4 h-quarters; each wave owns ONE i, all 64 j/chunk
// (2 jt-passes of 2, acc 24 regs). Chunk g-rows loaded once into BOTH P0/P1.
// 8 chunks, ~24 barriers. 1 block/CU (register wall: w1f+w2f ~156 regs in
// unified VGPR/AGPR file caps at 2 waves/SIMD; R1/R3 proved 2-block residency
// unreachable at this footprint).
// CORRECTNESS WALL — DO NOT MODIFY: five independent perturbations raced:
// R5 (.055), R6 (.156), R8 (.104) schedule restructures; R7 (.031) pure
// register prefetch; R10 (.096) pure s_setprio hint. A timing-sensitive
// hazard exists that this exact schedule masks; six full-ordering audits
// found no root cause. Counters at this state: MfmaUtil ~20, VALUBusy ~31,
// HBM 0.8% -> latency/barrier-bound, NOT a roofline; root-causing the race
// is the prerequisite for any further gain here.
#define OFF_P0   0        // P0 [64][528B] = 33792
#define OFF_P1   33792    // P1 [64][528B] -> 67584
#define OFF_H10  67584    // h1(i0) [64][336B] = 21504 -> 89088
#define OFF_H11  89088    // h1(i1) -> 110592
#define OFF_SB   110592   // [2][8][4][64] f32 = 16384 -> 126976
#define OFF_C2   126976   // b2 160 f32 = 640 -> 127616
#define OFF_W3L  127616   // W3 160 f32 = 640 -> 128256
#define LDS_SZ   128256
// transients (prologue only): W1t [150][272B]=40800, W2t [150][336B]=50400 — both < OFF_SB

__global__ __launch_bounds__(512, 2) void pairwise_mfma(
    const float* __restrict__ g,  const float* __restrict__ ms,
    const float* __restrict__ W1, const float* __restrict__ W2,
    const float* __restrict__ b2, const float* __restrict__ W3,
    const float* __restrict__ b3, const float* __restrict__ wsA,
    const unsigned short* __restrict__ wsB, float* __restrict__ out)
{
    extern __shared__ __attribute__((aligned(16))) char smem[];
    float* smf = (float*)smem;
    const int tid  = threadIdx.x;
    const int wave = tid >> 6;
    const int lane = tid & 63;
    const int c    = lane & 15;
    const int q    = lane >> 4;
    const int is   = wave >> 2;     // i-selector (0/1)
    const int wqr  = wave & 3;
    const int wq   = is ? (3 - wqr) : wqr;   // mirrored for SIMD load balance
    const int hbase  = (wq < 2) ? wq * 48 : 96 + (wq - 2) * 32;
    const int mcount = (wq < 2) ? 3 : 2;
    const short8 z8 = {0, 0, 0, 0, 0, 0, 0, 0};

    // ---- stage W1t (bf16 transposed, stride 272B) in 2 e-passes; 300 threads ----
    short8 w1f[3][8];
    for (int p = 0; p < 2; ++p) {
        if (p) __syncthreads();
        if (tid < 300) {
            const int h = (tid < 150) ? tid : tid - 150;
            const int half = (tid < 150) ? 0 : 1;
            const float* wsrc = W1 + (2 * E + p * 128) * H + h;
            char* dst = smem + h * 272 + half * 128;
#pragma unroll 4
            for (int t = 0; t < 32; ++t) {
                const int ep = half * 32 + t;
                *(unsigned*)(dst + t * 4) = pkbf(wsrc[(2 * ep) * H], wsrc[(2 * ep + 1) * H]);
            }
        }
        __syncthreads();
#pragma unroll
        for (int m = 0; m < 3; ++m) {
            const int hr = hbase + m * 16 + c;
#pragma unroll
            for (int ktp = 0; ktp < 4; ++ktp)
                w1f[m][p * 4 + ktp] = (m < mcount && hr < H)
                    ? *(const short8*)(smem + hr * 272 + (ktp * 32 + q * 8) * 2) : z8;
        }
    }
    __syncthreads();
    // ---- stage W2t (stride 336B); 300 threads; consts in parallel ----
    if (tid < 300) {
        const int h = (tid < 150) ? tid : tid - 150;
        const int half = (tid < 150) ? 0 : 1;
        char* dst = smem + h * 336;
#pragma unroll 4
        for (int t = 0; t < 42; ++t) {
            const int kp = half * 42 + t;
            const float lo = (2 * kp     < H) ? W2[(2 * kp) * H + h]     : 0.0f;
            const float hi = (2 * kp + 1 < H) ? W2[(2 * kp + 1) * H + h] : 0.0f;
            *(unsigned*)(dst + kp * 4) = pkbf(lo, hi);
        }
    }
    if (tid >= 320 && tid < 480) {
        const int hx = tid - 320;
        smf[OFF_C2 / 4 + hx]  = (hx < H) ? b2[hx] : 0.0f;
        smf[OFF_W3L / 4 + hx] = (hx < H) ? W3[hx] : 0.0f;
    }
    __syncthreads();
    short8 w2f[3][5];
#pragma unroll
    for (int m = 0; m < 3; ++m) {
        const int hr = hbase + m * 16 + c;
#pragma unroll
        for (int kt = 0; kt < 5; ++kt)
            w2f[m][kt] = (m < mcount && hr < H)
                ? *(const short8*)(smem + hr * 336 + (kt * 32 + q * 8) * 2) : z8;
    }
    __syncthreads();

    const int jb = tid >> 5;        // 0..15 (staging row group)
    const int e0 = (tid & 31) * 8;  // staging e-columns
    const float b3v = b3[0];
    const int i0 = blockIdx.x * 2;
    const int i  = i0 + is;         // this wave's compute i

    // staging scale vectors for BOTH i's (shared g-row loads feed both P buffers)
    const f32x4 ga0 = *(const f32x4*)(g + i0 * E + e0);
    const f32x4 gb0 = *(const f32x4*)(g + i0 * E + e0 + 4);
    const f32x4 ga1 = *(const f32x4*)(g + (i0 + 1) * E + e0);
    const f32x4 gb1 = *(const f32x4*)(g + (i0 + 1) * E + e0 + 4);

    f32x4 av[3];
#pragma unroll
    for (int m = 0; m < 3; ++m)
        av[m] = (m < mcount) ? *(const f32x4*)(wsA + i * HP + hbase + m * 16 + q * 4)
                             : (f32x4){0, 0, 0, 0};

    const int offP = is ? OFF_P1  : OFF_P0;
    const int offH = is ? OFF_H11 : OFF_H10;

    for (int ch = 0; ch < NCH; ++ch) {
        const int j0 = ch * JB;
        // ---- stage P0[jl][e]=gj*gi0, P1[jl][e]=gj*gi1 (4 rows/thread, gj loaded once) ----
#pragma unroll
        for (int it = 0; it < 4; ++it) {
            const int jl = jb + it * 16;
            const float* gr = g + (j0 + jl) * E + e0;
            const f32x4 u = *(const f32x4*)gr;
            const f32x4 v = *(const f32x4*)(gr + 4);
            uint4v pk;
            pk[0] = pkbf(u[0] * ga0[0], u[1] * ga0[1]);
            pk[1] = pkbf(u[2] * ga0[2], u[3] * ga0[3]);
            pk[2] = pkbf(v[0] * gb0[0], v[1] * gb0[1]);
            pk[3] = pkbf(v[2] * gb0[2], v[3] * gb0[3]);
            *(uint4v*)(smem + OFF_P0 + jl * 528 + e0 * 2) = pk;
            pk[0] = pkbf(u[0] * ga1[0], u[1] * ga1[1]);
            pk[1] = pkbf(u[2] * ga1[2], u[3] * ga1[3]);
            pk[2] = pkbf(v[0] * gb1[0], v[1] * gb1[1]);
            pk[3] = pkbf(v[2] * gb1[2], v[3] * gb1[3]);
            *(uint4v*)(smem + OFF_P1 + jl * 528 + e0 * 2) = pk;
        }
        __syncthreads();   // barrier A: P0/P1 visible

        // ---- layer 1 + epi 1, two jt-passes (acc stays 24 regs) ----
#pragma unroll
        for (int jp = 0; jp < 2; ++jp) {
            f32x4 acc[2][3];
#pragma unroll
            for (int jt = 0; jt < 2; ++jt)
#pragma unroll
                for (int m = 0; m < 3; ++m) acc[jt][m] = (f32x4){0, 0, 0, 0};
#pragma unroll
            for (int kt = 0; kt < 8; ++kt) {
                short8 pf[2];
#pragma unroll
                for (int jt = 0; jt < 2; ++jt)
                    pf[jt] = *(const short8*)(smem + offP + ((jp * 2 + jt) * 16 + c) * 528 + (kt * 32 + q * 8) * 2);
#pragma unroll
                for (int m = 0; m < 3; ++m)
                    if (m < mcount)
#pragma unroll
                        for (int jt = 0; jt < 2; ++jt)
                            acc[jt][m] = __builtin_amdgcn_mfma_f32_16x16x32_bf16(w1f[m][kt], pf[jt], acc[jt][m], 0, 0, 0);
            }
#pragma unroll
            for (int m = 0; m < 3; ++m)
                if (m < mcount) {
                    const int h0 = hbase + m * 16 + q * 4;
#pragma unroll
                    for (int jt = 0; jt < 2; ++jt) {
                        const int j = (jp * 2 + jt) * 16 + c;
                        const uint2v bv = *(const uint2v*)(wsB + (j0 + j) * HP + h0);
                        const float v0 = fmaxf(acc[jt][m][0] + av[m][0] + __uint_as_float(bv[0] << 16), 0.0f);
                        const float v1 = fmaxf(acc[jt][m][1] + av[m][1] + __uint_as_float(bv[0] & 0xffff0000u), 0.0f);
                        const float v2 = fmaxf(acc[jt][m][2] + av[m][2] + __uint_as_float(bv[1] << 16), 0.0f);
                        const float v3 = fmaxf(acc[jt][m][3] + av[m][3] + __uint_as_float(bv[1] & 0xffff0000u), 0.0f);
                        uint2v hw;
                        hw[0] = pkbf(v0, v1);
                        hw[1] = pkbf(v2, v3);
                        *(uint2v*)(smem + offH + j * 336 + h0 * 2) = hw;
                    }
                }
        }
        __syncthreads();   // barrier B: h1(i0), h1(i1) visible

        // ---- layer 2 + epi 2, two jt-passes ----
#pragma unroll
        for (int jp = 0; jp < 2; ++jp) {
            f32x4 acc[2][3];
#pragma unroll
            for (int jt = 0; jt < 2; ++jt)
#pragma unroll
                for (int m = 0; m < 3; ++m) acc[jt][m] = (f32x4){0, 0, 0, 0};
#pragma unroll
            for (int kt = 0; kt < 5; ++kt) {
                short8 hf[2];
#pragma unroll
                for (int jt = 0; jt < 2; ++jt)
                    hf[jt] = *(const short8*)(smem + offH + ((jp * 2 + jt) * 16 + c) * 336 + (kt * 32 + q * 8) * 2);
#pragma unroll
                for (int m = 0; m < 3; ++m)
                    if (m < mcount)
#pragma unroll
                        for (int jt = 0; jt < 2; ++jt)
                            acc[jt][m] = __builtin_amdgcn_mfma_f32_16x16x32_bf16(w2f[m][kt], hf[jt], acc[jt][m], 0, 0, 0);
            }
            float part[2] = {0.0f, 0.0f};
#pragma unroll
            for (int m = 0; m < 3; ++m)
                if (m < mcount) {
                    const int h0 = hbase + m * 16 + q * 4;
                    const f32x4 b2v = *(const f32x4*)(smf + OFF_C2 / 4 + h0);
                    const f32x4 w3v = *(const f32x4*)(smf + OFF_W3L / 4 + h0);
#pragma unroll
                    for (int jt = 0; jt < 2; ++jt)
#pragma unroll
                        for (int r = 0; r < 4; ++r)
                            part[jt] = fmaf(fmaxf(acc[jt][m][r] + b2v[r], 0.0f), w3v[r], part[jt]);
                }
#pragma unroll
            for (int jt = 0; jt < 2; ++jt) {
                float pv = part[jt];
                pv += __shfl_xor(pv, 16);
                pv += __shfl_xor(pv, 32);
                if (q == 0)
                    smf[OFF_SB / 4 + ((is * 8 + ch) * 4 + wq) * 64 + (jp * 2 + jt) * 16 + c] = pv;
            }
        }
        __syncthreads();   // barrier C: SB slot written; also protects P/h1 re-stage next chunk
    }

    // ---- single coalesced flush: 2 stores/thread, no per-chunk global stores ----
    {
        const float msj = ms[tid];
        const int chf = tid >> 6, jl = tid & 63;
#pragma unroll
        for (int is2 = 0; is2 < 2; ++is2) {
            const int iw = i0 + is2;
            const int base = OFF_SB / 4 + ((is2 * 8 + chf) * 4) * 64 + jl;
            const float s = smf[base] + smf[base + 64] + smf[base + 128] + smf[base + 192] + b3v;
            out[iw * N + tid] = (ms[iw] + msj + s) * (1.0f / 3.0f);
        }
    }
}

extern "C" void kernel_launch(void* const* d_in, const int* in_sizes, int n_in,
                              void* d_out, int out_size, void* d_ws, size_t ws_size,
                              hipStream_t stream) {
    const float* g  = (const float*)d_in[0];
    const float* ms = (const float*)d_in[1];
    const float* W1 = (const float*)d_in[2];
    const float* b1 = (const float*)d_in[3];
    const float* W2 = (const float*)d_in[4];
    const float* b2 = (const float*)d_in[5];
    const float* W3 = (const float*)d_in[6];
    const float* b3 = (const float*)d_in[7];
    float* out = (float*)d_out;
    float* wsA = (float*)d_ws;                                         // 512*160 f32
    unsigned short* wsB = (unsigned short*)((char*)d_ws + N * HP * 4); // 512*160 bf16

    static bool attr_set = false;
    if (!attr_set) {
        hipFuncSetAttribute((const void*)pairwise_mfma,
                            hipFuncAttributeMaxDynamicSharedMemorySize, LDS_SZ);
        attr_set = true;
    }

    precompute_ab<<<N, 192, 0, stream>>>(g, W1, b1, wsA, wsB);
    pairwise_mfma<<<N / 2, 512, LDS_SZ, stream>>>(g, ms, W1, W2, b2, W3, b3, wsA, wsB, out);
}

// Round 15
// 151.960 us; speedup vs baseline: 1.2483x; 1.0046x over previous
//
#include <hip/hip_runtime.h>

#define N  512
#define E  256
#define H  150
#define HP 160
#define JB 64          // j per chunk
#define NCH (N / JB)   // 8

typedef __attribute__((ext_vector_type(8))) short short8;
typedef __attribute__((ext_vector_type(4))) float f32x4;
typedef __attribute__((ext_vector_type(4))) unsigned uint4v;
typedef __attribute__((ext_vector_type(2))) unsigned uint2v;

// Manual RNE f32->bf16 (verified numerics; __float22bfloat162_rn truncates here).
__device__ __forceinline__ unsigned short f2bf(float f) {
    unsigned u = __float_as_uint(f);
    u += 0x7fffu + ((u >> 16) & 1u);          // RNE
    return (unsigned short)(u >> 16);
}
__device__ __forceinline__ unsigned pkbf(float a, float b) {
    return (unsigned)f2bf(a) | ((unsigned)f2bf(b) << 16);
}

// ---------------- kernel 1: A[i,h]=g_i@W1a + b1 (f32), B[j,h]=g_j@W1b (bf16) ----------------
// TERMINAL STATE (verified 152.65us @ R14): 512 blocks x 1 i -> 1536 waves
// (6/CU). Per-(i,h) FMA chain order/length fixed across R9/R12/R13 -> wsA/wsB
// bit-identical at every step; kernel-1 latency taken ~60us -> ~5us over the
// session (R9 unroll, R12/R13 TLP). Axis exhausted (R13 delta within noise).
__global__ __launch_bounds__(192) void precompute_ab(
    const float* __restrict__ g, const float* __restrict__ W1,
    const float* __restrict__ b1, float* __restrict__ wsA,
    unsigned short* __restrict__ wsB)
{
    const int i0  = blockIdx.x;
    const int tid = threadIdx.x;
    __shared__ float gi[E];
    for (int idx = tid; idx < E; idx += 192) gi[idx] = g[i0 * E + idx];
    __syncthreads();
    const int h = tid;
    if (h < HP) {
        float a = 0.0f, b = 0.0f;
        if (h < H) {
#pragma unroll 8
            for (int e = 0; e < E; ++e) {
                const float wa = W1[e * H + h];
                const float wb = W1[(E + e) * H + h];
                a = fmaf(gi[e], wa, a);
                b = fmaf(gi[e], wb, b);
            }
            a += b1[h];
        }
        wsA[i0 * HP + h] = a;
        wsB[i0 * HP + h] = f2bf(b);
    }
}

// ---------------- kernel 2: fused pairwise MFMA MLP ----------------
// R4/R9 VERBATIM — FROZEN (passed 7x, 6x at absmax exactly 0.0078125).
// 8 waves = 2 i-groups x 4 h-quarters; each wave owns ONE i, all 64 j/chunk
// (2 jt-passes of 2, acc 24 regs). Chunk g-rows loaded once into BOTH P0/P1.
// 8 chunks, ~24 barriers. 1 block/CU (register wall: w1f+w2f ~156 regs in
// unified VGPR/AGPR file caps at 2 waves/SIMD; R1/R3 proved 2-block residency
// unreachable at this footprint).
// CORRECTNESS WALL — DO NOT MODIFY: five independent perturbations raced:
// R5 (.055), R6 (.156), R8 (.104) schedule restructures; R7 (.031) pure
// register prefetch; R10 (.096) pure s_setprio hint (decisive: an inert
// priority hint changed output values -> timing-sensitive race masked by this
// exact schedule). Seven full-ordering audits found no root cause; further
// gains require hardware-level race isolation, not source edits.
// Counters at this state: MfmaUtil ~20, VALUBusy ~31, HBM 0.8% ->
// latency/barrier-bound, NOT a roofline.
#define OFF_P0   0        // P0 [64][528B] = 33792
#define OFF_P1   33792    // P1 [64][528B] -> 67584
#define OFF_H10  67584    // h1(i0) [64][336B] = 21504 -> 89088
#define OFF_H11  89088    // h1(i1) -> 110592
#define OFF_SB   110592   // [2][8][4][64] f32 = 16384 -> 126976
#define OFF_C2   126976   // b2 160 f32 = 640 -> 127616
#define OFF_W3L  127616   // W3 160 f32 = 640 -> 128256
#define LDS_SZ   128256
// transients (prologue only): W1t [150][272B]=40800, W2t [150][336B]=50400 — both < OFF_SB

__global__ __launch_bounds__(512, 2) void pairwise_mfma(
    const float* __restrict__ g,  const float* __restrict__ ms,
    const float* __restrict__ W1, const float* __restrict__ W2,
    const float* __restrict__ b2, const float* __restrict__ W3,
    const float* __restrict__ b3, const float* __restrict__ wsA,
    const unsigned short* __restrict__ wsB, float* __restrict__ out)
{
    extern __shared__ __attribute__((aligned(16))) char smem[];
    float* smf = (float*)smem;
    const int tid  = threadIdx.x;
    const int wave = tid >> 6;
    const int lane = tid & 63;
    const int c    = lane & 15;
    const int q    = lane >> 4;
    const int is   = wave >> 2;     // i-selector (0/1)
    const int wqr  = wave & 3;
    const int wq   = is ? (3 - wqr) : wqr;   // mirrored for SIMD load balance
    const int hbase  = (wq < 2) ? wq * 48 : 96 + (wq - 2) * 32;
    const int mcount = (wq < 2) ? 3 : 2;
    const short8 z8 = {0, 0, 0, 0, 0, 0, 0, 0};

    // ---- stage W1t (bf16 transposed, stride 272B) in 2 e-passes; 300 threads ----
    short8 w1f[3][8];
    for (int p = 0; p < 2; ++p) {
        if (p) __syncthreads();
        if (tid < 300) {
            const int h = (tid < 150) ? tid : tid - 150;
            const int half = (tid < 150) ? 0 : 1;
            const float* wsrc = W1 + (2 * E + p * 128) * H + h;
            char* dst = smem + h * 272 + half * 128;
#pragma unroll 4
            for (int t = 0; t < 32; ++t) {
                const int ep = half * 32 + t;
                *(unsigned*)(dst + t * 4) = pkbf(wsrc[(2 * ep) * H], wsrc[(2 * ep + 1) * H]);
            }
        }
        __syncthreads();
#pragma unroll
        for (int m = 0; m < 3; ++m) {
            const int hr = hbase + m * 16 + c;
#pragma unroll
            for (int ktp = 0; ktp < 4; ++ktp)
                w1f[m][p * 4 + ktp] = (m < mcount && hr < H)
                    ? *(const short8*)(smem + hr * 272 + (ktp * 32 + q * 8) * 2) : z8;
        }
    }
    __syncthreads();
    // ---- stage W2t (stride 336B); 300 threads; consts in parallel ----
    if (tid < 300) {
        const int h = (tid < 150) ? tid : tid - 150;
        const int half = (tid < 150) ? 0 : 1;
        char* dst = smem + h * 336;
#pragma unroll 4
        for (int t = 0; t < 42; ++t) {
            const int kp = half * 42 + t;
            const float lo = (2 * kp     < H) ? W2[(2 * kp) * H + h]     : 0.0f;
            const float hi = (2 * kp + 1 < H) ? W2[(2 * kp + 1) * H + h] : 0.0f;
            *(unsigned*)(dst + kp * 4) = pkbf(lo, hi);
        }
    }
    if (tid >= 320 && tid < 480) {
        const int hx = tid - 320;
        smf[OFF_C2 / 4 + hx]  = (hx < H) ? b2[hx] : 0.0f;
        smf[OFF_W3L / 4 + hx] = (hx < H) ? W3[hx] : 0.0f;
    }
    __syncthreads();
    short8 w2f[3][5];
#pragma unroll
    for (int m = 0; m < 3; ++m) {
        const int hr = hbase + m * 16 + c;
#pragma unroll
        for (int kt = 0; kt < 5; ++kt)
            w2f[m][kt] = (m < mcount && hr < H)
                ? *(const short8*)(smem + hr * 336 + (kt * 32 + q * 8) * 2) : z8;
    }
    __syncthreads();

    const int jb = tid >> 5;        // 0..15 (staging row group)
    const int e0 = (tid & 31) * 8;  // staging e-columns
    const float b3v = b3[0];
    const int i0 = blockIdx.x * 2;
    const int i  = i0 + is;         // this wave's compute i

    // staging scale vectors for BOTH i's (shared g-row loads feed both P buffers)
    const f32x4 ga0 = *(const f32x4*)(g + i0 * E + e0);
    const f32x4 gb0 = *(const f32x4*)(g + i0 * E + e0 + 4);
    const f32x4 ga1 = *(const f32x4*)(g + (i0 + 1) * E + e0);
    const f32x4 gb1 = *(const f32x4*)(g + (i0 + 1) * E + e0 + 4);

    f32x4 av[3];
#pragma unroll
    for (int m = 0; m < 3; ++m)
        av[m] = (m < mcount) ? *(const f32x4*)(wsA + i * HP + hbase + m * 16 + q * 4)
                             : (f32x4){0, 0, 0, 0};

    const int offP = is ? OFF_P1  : OFF_P0;
    const int offH = is ? OFF_H11 : OFF_H10;

    for (int ch = 0; ch < NCH; ++ch) {
        const int j0 = ch * JB;
        // ---- stage P0[jl][e]=gj*gi0, P1[jl][e]=gj*gi1 (4 rows/thread, gj loaded once) ----
#pragma unroll
        for (int it = 0; it < 4; ++it) {
            const int jl = jb + it * 16;
            const float* gr = g + (j0 + jl) * E + e0;
            const f32x4 u = *(const f32x4*)gr;
            const f32x4 v = *(const f32x4*)(gr + 4);
            uint4v pk;
            pk[0] = pkbf(u[0] * ga0[0], u[1] * ga0[1]);
            pk[1] = pkbf(u[2] * ga0[2], u[3] * ga0[3]);
            pk[2] = pkbf(v[0] * gb0[0], v[1] * gb0[1]);
            pk[3] = pkbf(v[2] * gb0[2], v[3] * gb0[3]);
            *(uint4v*)(smem + OFF_P0 + jl * 528 + e0 * 2) = pk;
            pk[0] = pkbf(u[0] * ga1[0], u[1] * ga1[1]);
            pk[1] = pkbf(u[2] * ga1[2], u[3] * ga1[3]);
            pk[2] = pkbf(v[0] * gb1[0], v[1] * gb1[1]);
            pk[3] = pkbf(v[2] * gb1[2], v[3] * gb1[3]);
            *(uint4v*)(smem + OFF_P1 + jl * 528 + e0 * 2) = pk;
        }
        __syncthreads();   // barrier A: P0/P1 visible

        // ---- layer 1 + epi 1, two jt-passes (acc stays 24 regs) ----
#pragma unroll
        for (int jp = 0; jp < 2; ++jp) {
            f32x4 acc[2][3];
#pragma unroll
            for (int jt = 0; jt < 2; ++jt)
#pragma unroll
                for (int m = 0; m < 3; ++m) acc[jt][m] = (f32x4){0, 0, 0, 0};
#pragma unroll
            for (int kt = 0; kt < 8; ++kt) {
                short8 pf[2];
#pragma unroll
                for (int jt = 0; jt < 2; ++jt)
                    pf[jt] = *(const short8*)(smem + offP + ((jp * 2 + jt) * 16 + c) * 528 + (kt * 32 + q * 8) * 2);
#pragma unroll
                for (int m = 0; m < 3; ++m)
                    if (m < mcount)
#pragma unroll
                        for (int jt = 0; jt < 2; ++jt)
                            acc[jt][m] = __builtin_amdgcn_mfma_f32_16x16x32_bf16(w1f[m][kt], pf[jt], acc[jt][m], 0, 0, 0);
            }
#pragma unroll
            for (int m = 0; m < 3; ++m)
                if (m < mcount) {
                    const int h0 = hbase + m * 16 + q * 4;
#pragma unroll
                    for (int jt = 0; jt < 2; ++jt) {
                        const int j = (jp * 2 + jt) * 16 + c;
                        const uint2v bv = *(const uint2v*)(wsB + (j0 + j) * HP + h0);
                        const float v0 = fmaxf(acc[jt][m][0] + av[m][0] + __uint_as_float(bv[0] << 16), 0.0f);
                        const float v1 = fmaxf(acc[jt][m][1] + av[m][1] + __uint_as_float(bv[0] & 0xffff0000u), 0.0f);
                        const float v2 = fmaxf(acc[jt][m][2] + av[m][2] + __uint_as_float(bv[1] << 16), 0.0f);
                        const float v3 = fmaxf(acc[jt][m][3] + av[m][3] + __uint_as_float(bv[1] & 0xffff0000u), 0.0f);
                        uint2v hw;
                        hw[0] = pkbf(v0, v1);
                        hw[1] = pkbf(v2, v3);
                        *(uint2v*)(smem + offH + j * 336 + h0 * 2) = hw;
                    }
                }
        }
        __syncthreads();   // barrier B: h1(i0), h1(i1) visible

        // ---- layer 2 + epi 2, two jt-passes ----
#pragma unroll
        for (int jp = 0; jp < 2; ++jp) {
            f32x4 acc[2][3];
#pragma unroll
            for (int jt = 0; jt < 2; ++jt)
#pragma unroll
                for (int m = 0; m < 3; ++m) acc[jt][m] = (f32x4){0, 0, 0, 0};
#pragma unroll
            for (int kt = 0; kt < 5; ++kt) {
                short8 hf[2];
#pragma unroll
                for (int jt = 0; jt < 2; ++jt)
                    hf[jt] = *(const short8*)(smem + offH + ((jp * 2 + jt) * 16 + c) * 336 + (kt * 32 + q * 8) * 2);
#pragma unroll
                for (int m = 0; m < 3; ++m)
                    if (m < mcount)
#pragma unroll
                        for (int jt = 0; jt < 2; ++jt)
                            acc[jt][m] = __builtin_amdgcn_mfma_f32_16x16x32_bf16(w2f[m][kt], hf[jt], acc[jt][m], 0, 0, 0);
            }
            float part[2] = {0.0f, 0.0f};
#pragma unroll
            for (int m = 0; m < 3; ++m)
                if (m < mcount) {
                    const int h0 = hbase + m * 16 + q * 4;
                    const f32x4 b2v = *(const f32x4*)(smf + OFF_C2 / 4 + h0);
                    const f32x4 w3v = *(const f32x4*)(smf + OFF_W3L / 4 + h0);
#pragma unroll
                    for (int jt = 0; jt < 2; ++jt)
#pragma unroll
                        for (int r = 0; r < 4; ++r)
                            part[jt] = fmaf(fmaxf(acc[jt][m][r] + b2v[r], 0.0f), w3v[r], part[jt]);
                }
#pragma unroll
            for (int jt = 0; jt < 2; ++jt) {
                float pv = part[jt];
                pv += __shfl_xor(pv, 16);
                pv += __shfl_xor(pv, 32);
                if (q == 0)
                    smf[OFF_SB / 4 + ((is * 8 + ch) * 4 + wq) * 64 + (jp * 2 + jt) * 16 + c] = pv;
            }
        }
        __syncthreads();   // barrier C: SB slot written; also protects P/h1 re-stage next chunk
    }

    // ---- single coalesced flush: 2 stores/thread, no per-chunk global stores ----
    {
        const float msj = ms[tid];
        const int chf = tid >> 6, jl = tid & 63;
#pragma unroll
        for (int is2 = 0; is2 < 2; ++is2) {
            const int iw = i0 + is2;
            const int base = OFF_SB / 4 + ((is2 * 8 + chf) * 4) * 64 + jl;
            const float s = smf[base] + smf[base + 64] + smf[base + 128] + smf[base + 192] + b3v;
            out[iw * N + tid] = (ms[iw] + msj + s) * (1.0f / 3.0f);
        }
    }
}

extern "C" void kernel_launch(void* const* d_in, const int* in_sizes, int n_in,
                              void* d_out, int out_size, void* d_ws, size_t ws_size,
                              hipStream_t stream) {
    const float* g  = (const float*)d_in[0];
    const float* ms = (const float*)d_in[1];
    const float* W1 = (const float*)d_in[2];
    const float* b1 = (const float*)d_in[3];
    const float* W2 = (const float*)d_in[4];
    const float* b2 = (const float*)d_in[5];
    const float* W3 = (const float*)d_in[6];
    const float* b3 = (const float*)d_in[7];
    float* out = (float*)d_out;
    float* wsA = (float*)d_ws;                                         // 512*160 f32
    unsigned short* wsB = (unsigned short*)((char*)d_ws + N * HP * 4); // 512*160 bf16

    static bool attr_set = false;
    if (!attr_set) {
        hipFuncSetAttribute((const void*)pairwise_mfma,
                            hipFuncAttributeMaxDynamicSharedMemorySize, LDS_SZ);
        attr_set = true;
    }

    precompute_ab<<<N, 192, 0, stream>>>(g, W1, b1, wsA, wsB);
    pairwise_mfma<<<N / 2, 512, LDS_SZ, stream>>>(g, ms, W1, W2, b2, W3, b3, wsA, wsB, out);
}